// Round 11
// baseline (283.103 us; speedup 1.0000x reference)
//
#include <hip/hip_runtime.h>

#define NND   8192
#define DDIM  256
#define NGRP  32
#define ZEROF 1e-8f
#define KSTR  72   // K-loop LDS row stride in u16 (144 B: bank stride 4 -> 2-way = free)
#define TSTR  72   // epilogue transpose tile stride in u16
#define CCAP 192   // reorder per-(bucket,seg-chunk) capacity (mean 64, +16 sigma)
// Round-11: fused 2-K-step body (K-block 64). Barrier pairs per block: 4 (was 8),
// mode1: 12 (was 24); per-step MLP 8-12 loads. LDS (u16): A 2x4608, B 2x(4608|9216)
// -> HALF 36 KB, FULL 54 KB, dynamic extern __shared__ sized per kernel.
#define SM_HALF 36864
#define SM_FULL 55296

typedef unsigned short u16;
typedef __attribute__((ext_vector_type(8))) short short8v;
typedef __attribute__((ext_vector_type(4))) float float4v;

__device__ inline u16 f2bf(float x) {
  unsigned u = __float_as_uint(x);
  u += 0x7fffu + ((u >> 16) & 1u);
  return (u16)(u >> 16);
}
__device__ inline float bf2f(u16 h) { return __uint_as_float((unsigned)h << 16); }
__device__ inline void split2(float x, u16& h, u16& l) {
  h = f2bf(x);
  l = f2bf(x - bf2f(h));
}

__device__ inline float wave_sum(float v) {
#pragma unroll
  for (int off = 32; off > 0; off >>= 1) v += __shfl_down(v, off, 64);
  return v;
}

// ================= unified split-bf16 MFMA GEMM body (fused 2-K-step) =================
// C-tile 64 x (HALF?64:128), 4 waves, 16x16x32 bf16 MFMA, split-bf16x3.
// MODE 0: XWT[c][node] = (H @ Wcat)^T       a=H(node), b=Wt(c)          [full]
// MODE 1: Hout = relu(b3 + M @ XWcat)       a=XWT(d), b=Mb h/l, K=768   [half]
// MODE 2: A_raw = x.xT (UNSCALED)           a=b=x                       [half]
// MODE 3: A = 0.5A + 0.5 sigmoid(t.HT)      a=tmp, b=H                  [half]
// MODE 5: A = 0.5*A_raw*scale + 0.5 sig(.)  a=tmp, b=H; scale=di*dj/(ni*nj+e) [half]
// MODE 4: tmp[node][d] = H @ T              a=Tt(d), b=H(node)          [half]
// NOTE (round-5 lesson): next-step loads issue AFTER the second barrier.
#define LOAD_REGS(tt, kk)                                                                   \
  {                                                                                         \
    int m_ = tid >> 2, kq_ = (tid & 3) * 8;                                                 \
    size_t aoff_;                                                                           \
    if (MODE == 1)                                                                          \
      aoff_ = (size_t)((tt) * 256 + bym * 64 + m_) * 8192 + (size_t)(g * 256 + (kk) + kq_); \
    else if (MODE == 2 || MODE == 3 || MODE == 5)                                           \
      aoff_ = (size_t)(g * 256 + bym * 64 + m_) * 256 + (kk) + kq_;                         \
    else                                                                                    \
      aoff_ = (size_t)(bym * 64 + m_) * 256 + (kk) + kq_;                                   \
    rA[0][0] = *(const short8v*)&Ah_g[aoff_];                                               \
    rA[0][1] = *(const short8v*)&Ah_g[aoff_ + 32];                                          \
    rA[1][0] = *(const short8v*)&Al_g[aoff_];                                               \
    rA[1][1] = *(const short8v*)&Al_g[aoff_ + 32];                                          \
    size_t bbase_ = (MODE == 1) ? ((size_t)(g * 3 + (tt)) << 16)                            \
                  : ((MODE == 2 || MODE == 3 || MODE == 5) ? ((size_t)g << 16) : (size_t)0);\
    if (HALF) {                                                                             \
      int n_ = tid & 63, kq2_ = (tid >> 6) * 8;                                             \
      size_t boff_ = bbase_ + (size_t)(col0 + n_) * 256 + (kk) + kq2_;                      \
      rB[0][0] = *(const short8v*)&Bh_g[boff_];                                             \
      rB[0][1] = *(const short8v*)&Bh_g[boff_ + 32];                                        \
      rB[1][0] = *(const short8v*)&Bl_g[boff_];                                             \
      rB[1][1] = *(const short8v*)&Bl_g[boff_ + 32];                                        \
    } else {                                                                                \
      int n_ = tid & 127, kq2_ = (tid >> 7) * 16;                                           \
      size_t boff_ = bbase_ + (size_t)(col0 + n_) * 256 + (kk) + kq2_;                      \
      rB[0][0] = *(const short8v*)&Bh_g[boff_];     rB[0][1] = *(const short8v*)&Bh_g[boff_ + 8];  \
      rB[0][2] = *(const short8v*)&Bh_g[boff_ + 32]; rB[0][3] = *(const short8v*)&Bh_g[boff_ + 40];\
      rB[1][0] = *(const short8v*)&Bl_g[boff_];     rB[1][1] = *(const short8v*)&Bl_g[boff_ + 8];  \
      rB[1][2] = *(const short8v*)&Bl_g[boff_ + 32]; rB[1][3] = *(const short8v*)&Bl_g[boff_ + 40];\
    }                                                                                       \
  }

template<int MODE, bool HALF>
__device__ __forceinline__ void mfma_body(
    u16* lds,
    const u16* __restrict__ Ah_g, const u16* __restrict__ Al_g,
    const u16* __restrict__ Bh_g, const u16* __restrict__ Bl_g,
    float* __restrict__ Cf, u16* __restrict__ Ch, u16* __restrict__ Cl,
    const float* __restrict__ nrm, const float* __restrict__ dinv,
    const float* __restrict__ bias,
    int bxm, int bym, int g) {
  u16* Ahs = lds;
  u16* Als = lds + 4608;
  u16* Bhs = lds + 9216;
  u16* Bls = lds + 9216 + (HALF ? 4608 : 9216);
  u16* Tt  = lds + 9216;      // aliases B region — only used after K-loop + sync
  const int NJ = HALF ? 2 : 4;
  const int tid = threadIdx.x;
  const int col0 = bxm * (HALF ? 64 : 128);
  const int w = tid >> 6, lane = tid & 63;
  const int lm = lane & 15, lq = lane >> 4;
  const int wr = (w >> 1) * 32, wc = (w & 1) * (HALF ? 32 : 64);

  float4v acc[2][4];
#pragma unroll
  for (int i = 0; i < 2; ++i)
#pragma unroll
    for (int j = 0; j < NJ; ++j) acc[i][j] = (float4v)0.f;

  short8v rA[2][2], rB[2][4];
  const int TOTAL = (MODE == 1) ? 12 : 4;   // fused 64-wide K blocks

  LOAD_REGS(0, 0);
  for (int step = 0; step < TOTAL; ++step) {
    if (step) __syncthreads();
    {
      int m = tid >> 2, kq = (tid & 3) * 8;
      *(short8v*)&Ahs[m * KSTR + kq]      = rA[0][0];
      *(short8v*)&Ahs[m * KSTR + kq + 32] = rA[0][1];
      *(short8v*)&Als[m * KSTR + kq]      = rA[1][0];
      *(short8v*)&Als[m * KSTR + kq + 32] = rA[1][1];
    }
    if (HALF) {
      int n = tid & 63, kq2 = (tid >> 6) * 8;
      *(short8v*)&Bhs[n * KSTR + kq2]      = rB[0][0];
      *(short8v*)&Bhs[n * KSTR + kq2 + 32] = rB[0][1];
      *(short8v*)&Bls[n * KSTR + kq2]      = rB[1][0];
      *(short8v*)&Bls[n * KSTR + kq2 + 32] = rB[1][1];
    } else {
      int n = tid & 127, kq2 = (tid >> 7) * 16;
      *(short8v*)&Bhs[n * KSTR + kq2]      = rB[0][0];
      *(short8v*)&Bhs[n * KSTR + kq2 + 8]  = rB[0][1];
      *(short8v*)&Bhs[n * KSTR + kq2 + 32] = rB[0][2];
      *(short8v*)&Bhs[n * KSTR + kq2 + 40] = rB[0][3];
      *(short8v*)&Bls[n * KSTR + kq2]      = rB[1][0];
      *(short8v*)&Bls[n * KSTR + kq2 + 8]  = rB[1][1];
      *(short8v*)&Bls[n * KSTR + kq2 + 32] = rB[1][2];
      *(short8v*)&Bls[n * KSTR + kq2 + 40] = rB[1][3];
    }
    __syncthreads();
    int nxt = step + 1;
    if (nxt < TOTAL) {
      if (MODE == 1) { LOAD_REGS(nxt >> 2, (nxt & 3) * 64); }
      else           { LOAD_REGS(0, nxt * 64); }
    }
#pragma unroll
    for (int sub = 0; sub < 2; ++sub) {
      const int co = sub * 32 + lq * 8;
      short8v ah[2], al[2], bh[4], bl[4];
#pragma unroll
      for (int i = 0; i < 2; ++i) {
        int r = wr + i * 16 + lm;
        ah[i] = *(const short8v*)&Ahs[r * KSTR + co];
        al[i] = *(const short8v*)&Als[r * KSTR + co];
      }
#pragma unroll
      for (int j = 0; j < NJ; ++j) {
        int r = wc + j * 16 + lm;
        bh[j] = *(const short8v*)&Bhs[r * KSTR + co];
        bl[j] = *(const short8v*)&Bls[r * KSTR + co];
      }
#pragma unroll
      for (int i = 0; i < 2; ++i)
#pragma unroll
        for (int j = 0; j < NJ; ++j) {
          acc[i][j] = __builtin_amdgcn_mfma_f32_16x16x32_bf16(ah[i], bh[j], acc[i][j], 0, 0, 0);
          acc[i][j] = __builtin_amdgcn_mfma_f32_16x16x32_bf16(ah[i], bl[j], acc[i][j], 0, 0, 0);
          acc[i][j] = __builtin_amdgcn_mfma_f32_16x16x32_bf16(al[i], bh[j], acc[i][j], 0, 0, 0);
        }
    }
  }

  // ---- epilogues (frag: col=lm, row=lq*4+r) ----
  if (MODE == 2 || MODE == 3 || MODE == 5) {
#pragma unroll
    for (int i = 0; i < 2; ++i) {
#pragma unroll
      for (int r = 0; r < 4; ++r) {
        int grow = g * 256 + bym * 64 + wr + i * 16 + lq * 4 + r;
        float di = 0.f, ni = 0.f;
        if (MODE == 5) { di = dinv[grow]; ni = nrm[grow]; }
#pragma unroll
        for (int j = 0; j < NJ; ++j) {
          int gcol = col0 + wc + j * 16 + lm;
          size_t ci = (size_t)grow * 256 + gcol;
          float v = acc[i][j][r];
          if (MODE == 2) {
            Cf[ci] = v;                      // RAW dot; scale deferred to MODE 5 (D-l0)
          } else if (MODE == 3) {
            Cf[ci] = 0.5f * Cf[ci] + 0.5f * (1.f / (1.f + expf(-v)));
          } else {
            int gj = g * 256 + gcol;
            float scale = di * dinv[gj] / (ni * nrm[gj] + ZEROF);
            Cf[ci] = 0.5f * Cf[ci] * scale + 0.5f * (1.f / (1.f + expf(-v)));
          }
        }
      }
    }
  } else {
    float bsum[8];
    if (MODE == 1) {
#pragma unroll
      for (int i = 0; i < 2; ++i)
#pragma unroll
        for (int r = 0; r < 4; ++r) {
          int d = bym * 64 + wr + i * 16 + lq * 4 + r;
          bsum[i * 4 + r] = bias[d] + bias[256 + d] + bias[512 + d];
        }
    }
    u16 hv[32], lv[32];
#pragma unroll
    for (int i = 0; i < 2; ++i)
#pragma unroll
      for (int j = 0; j < NJ; ++j)
#pragma unroll
        for (int r = 0; r < 4; ++r) {
          float v = acc[i][j][r];
          if (MODE == 1) v = fmaxf(v + bsum[i * 4 + r], 0.f);
          split2(v, hv[(i * 4 + r) * NJ + j], lv[(i * 4 + r) * NJ + j]);
        }
    int ebase1 = (MODE == 1) ? (g * 256 + col0) : col0;
    int ebase2 = bym * 64;
    size_t estride = (MODE == 0) ? 8192 : 256;
#pragma unroll
    for (int ph = 0; ph < 2; ++ph) {
      __syncthreads();
      const u16* sv = ph ? lv : hv;
#pragma unroll
      for (int i = 0; i < 2; ++i)
#pragma unroll
        for (int j = 0; j < NJ; ++j)
#pragma unroll
          for (int r = 0; r < 4; ++r)
            Tt[(wc + j * 16 + lm) * TSTR + wr + i * 16 + lq * 4 + r] = sv[(i * 4 + r) * NJ + j];
      __syncthreads();
      u16* dst = ph ? Cl : Ch;
      int cc0 = tid >> 3, mm0 = (tid & 7) * 8;
#pragma unroll
      for (int it = 0; it < (HALF ? 2 : 4); ++it) {
        int cc = it * 32 + cc0;
        short8v v = *(const short8v*)&Tt[cc * TSTR + mm0];
        *(short8v*)&dst[(size_t)(ebase1 + cc) * estride + ebase2 + mm0] = v;
      }
    }
  }
}

// ---- M-build block body: dense 32x256 fp32 tile from BUCKET-MAJOR records ----
__device__ __forceinline__ void mbuild_body(
    float* tile, int bid, int l,
    const uint2* __restrict__ recs2, const int* __restrict__ bcnt2,
    const float* __restrict__ Abuf, u16* __restrict__ Mbh, u16* __restrict__ Mbl) {
  const int tid = threadIdx.x;
  int gt = bid >> 3, chunk = bid & 7;
  int g = gt / 3;
  float4 z = make_float4(0.f, 0.f, 0.f, 0.f);
#pragma unroll
  for (int k = 0; k < 8; ++k) ((float4*)tile)[k * 256 + tid] = z;
  __syncthreads();
#pragma unroll
  for (int c = 0; c < 8; ++c) {
    int cnt = bcnt2[bid * 8 + c];
    const uint2* rp = &recs2[(size_t)bid * (8 * CCAP) + (size_t)c * CCAP];
    for (int k = tid; k < cnt; k += 256) {
      uint2 r = rp[k];
      int s = r.x & 255, d5 = (r.x >> 8) & 31;
      float w = l ? Abuf[(size_t)(g * 256 + s) * 256 + chunk * 32 + d5]
                  : __uint_as_float(r.y);
      atomicAdd(&tile[d5 * 256 + s], w);
    }
  }
  __syncthreads();
  size_t base4 = ((size_t)gt << 14) + ((size_t)chunk << 11);  // ushort4 units
#pragma unroll
  for (int k = 0; k < 8; ++k) {
    float4 f = ((float4*)tile)[k * 256 + tid];
    ushort4 h, lo;
    split2(f.x, h.x, lo.x); split2(f.y, h.y, lo.y);
    split2(f.z, h.z, lo.z); split2(f.w, h.w, lo.w);
    ((ushort4*)Mbh)[base4 + k * 256 + tid] = h;
    ((ushort4*)Mbl)[base4 + k * 256 + tid] = lo;
  }
}

// ===== prep: mask cvt | edge bucketing (atomic-free) | transpose/split W | norms+x-split =====
__global__ void k_prep(const int* __restrict__ e0, const int* __restrict__ e1,
                       const int* __restrict__ e2, const unsigned char* __restrict__ m0,
                       const unsigned char* __restrict__ m1,
                       const float* __restrict__ W, const float* __restrict__ T,
                       const float* __restrict__ x,
                       const float* __restrict__ ew0, const float* __restrict__ ew1,
                       const float* __restrict__ ew2,
                       float* __restrict__ emf, float* __restrict__ pmf,
                       u16* __restrict__ Wth, u16* __restrict__ Wtl,
                       u16* __restrict__ sct, uint2* __restrict__ recs,
                       float* __restrict__ nrm, float* __restrict__ Spart,
                       u16* __restrict__ Hh, u16* __restrict__ Hl,
                       int E_, int nCvt, int nBkt) {
  __shared__ float tile[32][33];
  __shared__ float inv[64];
  __shared__ int nz[1];
  __shared__ unsigned int hcnt[768];
  __shared__ unsigned int hoff[768];
  __shared__ unsigned int ppart[256];
  __shared__ uint2 stage[768];
  const int b = blockIdx.x, tid = threadIdx.x;
  if (b < nCvt) {
    // ---- mask dtype detect + convert (2*NND values) ----
    if (tid == 0) nz[0] = 0;
    __syncthreads();
    int i4 = tid * 4;
    int c = (m0[i4 + 1] != 0) + (m0[i4 + 2] != 0) + (m0[i4 + 3] != 0);
    if (c) atomicAdd(&nz[0], c);
    __syncthreads();
    int fM = (nz[0] == 0);
    int i = b * 256 + tid;
    if (i < NND) {
      unsigned char v = fM ? m0[4 * i] : m0[i];
      emf[i] = 1.f - (float)(v != 0);
    } else {
      int j = i - NND;
      unsigned char v = fM ? m1[4 * j] : m1[j];
      pmf[j] = 1.f - (float)(v != 0);
    }
  } else if (b < nCvt + nBkt) {
    // ---- atomic-free edge bucketing: block-private segments, LDS hist+scan ----
    if (tid == 0) nz[0] = 0;
    hcnt[tid] = 0; hcnt[tid + 256] = 0; hcnt[tid + 512] = 0;
    __syncthreads();
    if (e0[2 * tid + 1] != 0) atomicAdd(&nz[0], 1);
    __syncthreads();
    int fE = (nz[0] == 0);   // int64-format edges
    int e = (b - nCvt) * 256 + tid;
    bool valid = (e < E_);
    int mybid[3]; unsigned int myrec[3]; float myw[3];
    if (valid) {
#pragma unroll
      for (int t = 0; t < 3; ++t) {
        const int* ei = (t == 0) ? e0 : ((t == 1) ? e1 : e2);
        int src = fE ? ei[2 * e] : ei[e];
        int dst = fE ? ei[2 * (E_ + e)] : ei[E_ + e];
        int g = src >> 8, s = src & 255, d = dst & 255;
        mybid[t] = ((g * 3 + t) << 3) | (d >> 5);
        myrec[t] = (unsigned)(((d & 31) << 8) | s);
        myw[t] = (t == 0 ? ew0 : (t == 1 ? ew1 : ew2))[e];
        atomicAdd(&hcnt[mybid[t]], 1u);
      }
    }
    __syncthreads();
    unsigned c0 = hcnt[3 * tid], c1 = hcnt[3 * tid + 1], c2 = hcnt[3 * tid + 2];
    unsigned tsum = c0 + c1 + c2;
    ppart[tid] = tsum;
    __syncthreads();
    for (int off = 1; off < 256; off <<= 1) {
      unsigned v = (tid >= off) ? ppart[tid - off] : 0u;
      __syncthreads();
      ppart[tid] += v;
      __syncthreads();
    }
    unsigned base = ppart[tid] - tsum;   // exclusive prefix
    hoff[3 * tid] = base;
    hoff[3 * tid + 1] = base + c0;
    hoff[3 * tid + 2] = base + c0 + c1;
    __syncthreads();
#pragma unroll
    for (int k = 0; k < 3; ++k) {
      int bin = tid + k * 256;
      unsigned cc = hcnt[bin]; if (cc > 31u) cc = 31u;
      sct[(size_t)(b - nCvt) * 768 + bin] = (u16)(hoff[bin] | (cc << 11));
    }
    __syncthreads();
    if (valid) {
#pragma unroll
      for (int t = 0; t < 3; ++t) {
        unsigned slot = atomicAdd(&hoff[mybid[t]], 1u);
        stage[slot] = make_uint2(myrec[t], __float_as_uint(myw[t]));
      }
    }
    __syncthreads();
    uint2* dstp = &recs[(size_t)(b - nCvt) * 768];
    dstp[tid] = stage[tid];
    dstp[tid + 256] = stage[tid + 256];
    dstp[tid + 512] = stage[tid + 512];
  } else if (b < nCvt + nBkt + 512) {
    int bb = b - nCvt - nBkt;
    int mat = bb >> 6, rem = bb & 63;
    int k0 = (rem >> 3) * 32, n0 = (rem & 7) * 32;
    const float* src = (mat < 6) ? (W + (size_t)mat * 65536) : (T + (size_t)(mat - 6) * 65536);
    int r = tid >> 3, c4 = (tid & 7) * 4;
    const float4 v = *(const float4*)&src[(size_t)(k0 + r) * 256 + n0 + c4];
    tile[r][c4 + 0] = v.x; tile[r][c4 + 1] = v.y; tile[r][c4 + 2] = v.z; tile[r][c4 + 3] = v.w;
    __syncthreads();
    float o[4] = {tile[c4 + 0][r], tile[c4 + 1][r], tile[c4 + 2][r], tile[c4 + 3][r]};
    u16 hh[4], ll[4];
#pragma unroll
    for (int q = 0; q < 4; ++q) split2(o[q], hh[q], ll[q]);
    size_t off = (size_t)mat * 65536 + (size_t)(n0 + r) * 256 + k0 + c4;
    *(ushort4*)&Wth[off] = *(ushort4*)hh;
    *(ushort4*)&Wtl[off] = *(ushort4*)ll;
  } else {
    int bn = b - nCvt - nBkt - 512;    // 0..127
    int n0 = bn * 64;
    int w = tid >> 6, lane = tid & 63;
    for (int it = 0; it < 16; ++it) {
      int nl = it * 4 + w;
      int node = n0 + nl;
      const float4 v = *(const float4*)&x[(size_t)node * 256 + lane * 4];
      u16 hh[4], ll[4];
      split2(v.x, hh[0], ll[0]); split2(v.y, hh[1], ll[1]);
      split2(v.z, hh[2], ll[2]); split2(v.w, hh[3], ll[3]);
      *(ushort4*)&Hh[(size_t)node * 256 + lane * 4] = *(ushort4*)hh;
      *(ushort4*)&Hl[(size_t)node * 256 + lane * 4] = *(ushort4*)ll;
      float s = wave_sum(v.x * v.x + v.y * v.y + v.z * v.z + v.w * v.w);
      if (lane == 0) { float nr = sqrtf(s); nrm[node] = nr; inv[nl] = 1.f / nr; }
    }
    __syncthreads();
    float s = 0.f;
    for (int i = 0; i < 64; ++i) s += x[(size_t)(n0 + i) * 256 + tid] * inv[i];
    Spart[bn * 256 + tid] = s;
  }
}

// ==== k_reorder: WAVE per (bucket,chunk); lane i owns segment i; shfl prefix-sum ====
__global__ void k_reorder(const u16* __restrict__ sct, const uint2* __restrict__ recs,
                          uint2* __restrict__ recs2, int* __restrict__ bcnt2, int nBkt) {
  const int wid = blockIdx.x * 4 + (threadIdx.x >> 6);  // 0..6143
  const int lane = threadIdx.x & 63;
  const int bid = wid >> 3;       // bucket 0..767
  const int c = wid & 7;          // chunk 0..7
  const int nseg = nBkt >> 3;     // 64 for E=131072
  unsigned cnt = 0, start = 0;
  int bb = c * nseg + lane;
  if (lane < nseg) {
    unsigned sc = sct[(size_t)bb * 768 + bid];
    start = sc & 2047u; cnt = sc >> 11;
  }
  unsigned pre = cnt;
#pragma unroll
  for (int off = 1; off < 64; off <<= 1) {
    unsigned v = __shfl_up(pre, off, 64);
    if (lane >= off) pre += v;
  }
  unsigned excl = pre - cnt;
  unsigned total = __shfl(pre, 63, 64);
  uint2* dst = &recs2[(size_t)bid * (8 * CCAP) + (size_t)c * CCAP];
  const uint2* rp = &recs[(size_t)bb * 768 + start];
  for (unsigned k = 0; k < cnt; ++k) {
    unsigned o = excl + k;
    if (o < CCAP) dst[o] = rp[k];
  }
  if (lane == 0) bcnt2[bid * 8 + c] = (total > CCAP) ? CCAP : total;
}

// ==== stage A (l0, max heterogeneous pack):
//  mode0 GEMM l0 (768) | M-build l0 (768) | mode2 RAW x.xT (512) | dinv (128) ====
__global__ __launch_bounds__(256, 2) void k_stageA(
    const u16* __restrict__ Hinh, const u16* __restrict__ Hinl,
    const u16* __restrict__ Wth, const u16* __restrict__ Wtl,
    u16* __restrict__ XWTh, u16* __restrict__ XWTl,
    const uint2* __restrict__ recs2, const int* __restrict__ bcnt2,
    u16* __restrict__ Mbh, u16* __restrict__ Mbl,
    float* __restrict__ Abuf,
    const float* __restrict__ x, const float* __restrict__ Spart,
    const float* __restrict__ nrm, float* __restrict__ dinv) {
  extern __shared__ u16 lds[];
  const int b = blockIdx.x;
  if (b < 768) {
    mfma_body<0, false>(lds, Hinh, Hinl, Wth, Wtl,
                        nullptr, XWTh, XWTl, nullptr, nullptr, nullptr,
                        b >> 7, b & 127, 0);
  } else if (b < 1536) {
    mbuild_body((float*)lds, b - 768, 0, recs2, bcnt2, nullptr, Mbh, Mbl);
  } else if (b < 2048) {
    int bb = b - 1536;
    int g = bb & 31, r = bb >> 5;      // r: 0..15 -> bxm 0..3, bym 0..3
    mfma_body<2, true>(lds, Hinh, Hinl, Hinh, Hinl, Abuf, nullptr, nullptr,
                       nullptr, nullptr, nullptr, r >> 2, r & 3, g);
  } else {
    float* Sl = (float*)lds;
    const int tid = threadIdx.x;
    float s = 0.f;
    for (int bb = 0; bb < 128; ++bb) s += Spart[bb * 256 + tid];
    Sl[tid] = s;
    __syncthreads();
    int base = (b - 2048) * 64;
    int w = tid >> 6, lane = tid & 63;
    const float4 sv = *(const float4*)&Sl[lane * 4];
    for (int it = 0; it < 16; ++it) {
      int node = base + it * 4 + w;
      const float4 v = *(const float4*)&x[(size_t)node * 256 + lane * 4];
      float s2 = wave_sum(v.x * sv.x + v.y * sv.y + v.z * sv.z + v.w * sv.w);
      if (lane == 0) {
        float rowsum = s2 / nrm[node];
        dinv[node] = rsqrtf(fabsf(rowsum) + ZEROF);
      }
    }
  }
}

// ==== stage A2 (l1, fused heterogeneous pack): mode0 GEMM l1 (768) | M-build l1 (768) ====
__global__ __launch_bounds__(256, 2) void k_stageA2(
    const u16* __restrict__ H2h, const u16* __restrict__ H2l,
    const u16* __restrict__ Wth, const u16* __restrict__ Wtl,
    u16* __restrict__ XWTh, u16* __restrict__ XWTl,
    const uint2* __restrict__ recs2, const int* __restrict__ bcnt2,
    const float* __restrict__ Abuf,
    u16* __restrict__ Mbh, u16* __restrict__ Mbl) {
  extern __shared__ u16 lds[];
  const int b = blockIdx.x;
  if (b < 768) {
    mfma_body<0, false>(lds, H2h, H2l, Wth + (size_t)768 * 256, Wtl + (size_t)768 * 256,
                        nullptr, XWTh, XWTl, nullptr, nullptr, nullptr,
                        b >> 7, b & 127, 0);
  } else {
    mbuild_body((float*)lds, b - 768, 1, recs2, bcnt2, Abuf, Mbh, Mbl);
  }
}

// ==== stage B: mode1 only (HALF 64x64, 512 blocks) ====
__global__ __launch_bounds__(256, 2) void k_stageB(
    const u16* __restrict__ XWTh, const u16* __restrict__ XWTl,
    const u16* __restrict__ Mbh, const u16* __restrict__ Mbl,
    u16* __restrict__ Houth, u16* __restrict__ Houtl, const float* __restrict__ bias) {
  extern __shared__ u16 lds[];
  const int b = blockIdx.x;
  int g = b & 31, r = b >> 5;          // r: 0..15 -> bxm 0..3, bym 0..3
  mfma_body<1, true>(lds, XWTh, XWTl, Mbh, Mbl,
                     nullptr, Houth, Houtl, nullptr, nullptr, bias,
                     r >> 2, r & 3, g);
}

// ============ stage C: mode4 (half, 512): tmp = H @ T ============
__global__ __launch_bounds__(256, 2) void k_stageC(
    const u16* __restrict__ Wth, const u16* __restrict__ Wtl, int l,
    const u16* __restrict__ Hh, const u16* __restrict__ Hl,
    u16* __restrict__ tmph, u16* __restrict__ tmpl) {
  extern __shared__ u16 lds[];
  const int b = blockIdx.x;
  mfma_body<4, true>(lds, Wth + (size_t)(6 + l) * 65536, Wtl + (size_t)(6 + l) * 65536,
                     Hh, Hl, nullptr, tmph, tmpl, nullptr, nullptr, nullptr,
                     b & 127, b >> 7, 0);
}

// ============ stage D: A update. scaled!=0 (l0): MODE 5 applies the deferred scale ============
__global__ __launch_bounds__(256, 2) void k_stageD(
    const u16* __restrict__ tmph, const u16* __restrict__ tmpl,
    const u16* __restrict__ Hh, const u16* __restrict__ Hl,
    float* __restrict__ Abuf,
    const float* __restrict__ nrm, const float* __restrict__ dinv, int scaled) {
  extern __shared__ u16 lds[];
  const int b = blockIdx.x;
  int g = b & 31, r = b >> 5;
  if (scaled)
    mfma_body<5, true>(lds, tmph, tmpl, Hh, Hl, Abuf, nullptr, nullptr,
                       nrm, dinv, nullptr, r >> 2, r & 3, g);
  else
    mfma_body<3, true>(lds, tmph, tmpl, Hh, Hl, Abuf, nullptr, nullptr,
                       nullptr, nullptr, nullptr, r >> 2, r & 3, g);
}

// ============ fused maps ============
__global__ void k_maps(const float* __restrict__ Abuf, const float* __restrict__ emf,
                       const float* __restrict__ pmf, float* __restrict__ out) {
  __shared__ float sme[256], smp[256], red[256];
  const int g = blockIdx.x, tid = threadIdx.x, w = tid >> 6, lane = tid & 63;
  const int j0 = g * 256 + lane * 4;
  const float4 pmv = *(const float4*)&pmf[j0];
  const float4 emv = *(const float4*)&emf[j0];
  for (int it = 0; it < 64; ++it) {
    int nl = it * 4 + w;
    const float4 a = *(const float4*)&Abuf[((size_t)g * 256 + nl) * 256 + lane * 4];
    float me = a.x * pmv.x + a.y * pmv.y + a.z * pmv.z + a.w * pmv.w;
    float mp = a.x * emv.x + a.y * emv.y + a.z * emv.z + a.w * emv.w;
#pragma unroll
    for (int off = 32; off > 0; off >>= 1) {
      me += __shfl_down(me, off, 64);
      mp += __shfl_down(mp, off, 64);
    }
    if (lane == 0) { sme[nl] = me; smp[nl] = mp; }
  }
  __syncthreads();
  for (int which = 0; which < 2; ++which) {
    float v = which ? smp[tid] : sme[tid];
    red[tid] = v; __syncthreads();
    for (int s = 128; s > 0; s >>= 1) { if (tid < s) red[tid] = fminf(red[tid], red[tid + s]); __syncthreads(); }
    float mn = red[0]; __syncthreads();
    red[tid] = v; __syncthreads();
    for (int s = 128; s > 0; s >>= 1) { if (tid < s) red[tid] = fmaxf(red[tid], red[tid + s]); __syncthreads(); }
    float mx = red[0]; __syncthreads();
    float m = (v - mn) / (mx - mn + ZEROF);
    red[tid] = m; __syncthreads();
    for (int s = 128; s > 0; s >>= 1) { if (tid < s) red[tid] += red[tid + s]; __syncthreads(); }
    float sum = red[0]; __syncthreads();
    out[which * NND + g * 256 + tid] = m / (sum + ZEROF);
  }
}

// ================= launch =================
extern "C" void kernel_launch(void* const* d_in, const int* in_sizes, int n_in,
                              void* d_out, int out_size, void* d_ws, size_t ws_size,
                              hipStream_t stream) {
  const float* x = (const float*)d_in[0];
  const unsigned char* em_raw = (const unsigned char*)d_in[7];
  const unsigned char* pm_raw = (const unsigned char*)d_in[8];
  const float* W  = (const float*)d_in[9];
  const float* bg = (const float*)d_in[10];
  const float* T  = (const float*)d_in[11];
  float* out = (float*)d_out;
  const int E_ = in_sizes[2];

  const int nCvt = (2 * NND) / 256;          // 64
  const int nBkt = (E_ + 255) / 256;         // 512 for E=131072

  float* ws = (float*)d_ws;
  size_t o = 0;
  float* Abuf = ws + o; o += (size_t)NND * 256;
  u16* Mbh_l0 = (u16*)(ws + o); o += (size_t)NGRP * 3 * 65536 / 2;
  u16* Mbl_l0 = (u16*)(ws + o); o += (size_t)NGRP * 3 * 65536 / 2;
  u16* Mbh_l1 = (u16*)(ws + o); o += (size_t)NGRP * 3 * 65536 / 2;
  u16* Mbl_l1 = (u16*)(ws + o); o += (size_t)NGRP * 3 * 65536 / 2;
  u16* Hh   = (u16*)(ws + o); o += (size_t)NND * 256 / 2;
  u16* Hl   = (u16*)(ws + o); o += (size_t)NND * 256 / 2;
  u16* H2h  = (u16*)(ws + o); o += (size_t)NND * 256 / 2;
  u16* H2l  = (u16*)(ws + o); o += (size_t)NND * 256 / 2;
  u16* tmph = (u16*)(ws + o); o += (size_t)NND * 256 / 2;
  u16* tmpl = (u16*)(ws + o); o += (size_t)NND * 256 / 2;
  u16* XWTh = (u16*)(ws + o); o += (size_t)768 * NND / 2;
  u16* XWTl = (u16*)(ws + o); o += (size_t)768 * NND / 2;
  u16* Wth  = (u16*)(ws + o); o += (size_t)8 * 65536 / 2;
  u16* Wtl  = (u16*)(ws + o); o += (size_t)8 * 65536 / 2;
  float* nrm   = ws + o; o += NND;
  float* dinv  = ws + o; o += NND;
  float* Spart = ws + o; o += 128 * 256;
  float* emf   = ws + o; o += NND;
  float* pmf   = ws + o; o += NND;
  u16* sct     = (u16*)(ws + o); o += (size_t)nBkt * 768 / 2;
  uint2* recs  = (uint2*)(ws + o); o += (size_t)nBkt * 768 * 2;
  uint2* recs2 = (uint2*)(ws + o); o += (size_t)768 * 8 * CCAP * 2;
  int* bcnt2   = (int*)(ws + o); o += (size_t)768 * 8;

  const float* ew0 = (const float*)d_in[2];
  const float* ew1 = (const float*)d_in[4];
  const float* ew2 = (const float*)d_in[6];

  k_prep<<<nCvt + nBkt + 512 + 128, 256, 0, stream>>>(
      (const int*)d_in[1], (const int*)d_in[3], (const int*)d_in[5], em_raw, pm_raw,
      W, T, x, ew0, ew1, ew2, emf, pmf, Wth, Wtl, sct, recs,
      nrm, Spart, Hh, Hl, E_, nCvt, nBkt);

  k_reorder<<<1536, 256, 0, stream>>>(sct, recs, recs2, bcnt2, nBkt);

  // ---- layer 0 ----
  k_stageA<<<2176, 256, SM_FULL, stream>>>(Hh, Hl, Wth, Wtl, XWTh, XWTl,
                                           recs2, bcnt2, Mbh_l0, Mbl_l0, Abuf,
                                           x, Spart, nrm, dinv);
  k_stageB<<<512, 256, SM_HALF, stream>>>(XWTh, XWTl, Mbh_l0, Mbl_l0, H2h, H2l, bg);
  k_stageC<<<512, 256, SM_HALF, stream>>>(Wth, Wtl, 0, H2h, H2l, tmph, tmpl);
  k_stageD<<<512, 256, SM_HALF, stream>>>(tmph, tmpl, H2h, H2l, Abuf, nrm, dinv, 1);

  // ---- layer 1 ----
  k_stageA2<<<1536, 256, SM_FULL, stream>>>(H2h, H2l, Wth, Wtl, XWTh, XWTl,
                                            recs2, bcnt2, Abuf, Mbh_l1, Mbl_l1);
  k_stageB<<<512, 256, SM_HALF, stream>>>(XWTh, XWTl, Mbh_l1, Mbl_l1, Hh, Hl, bg + 768);
  k_stageC<<<512, 256, SM_HALF, stream>>>(Wth, Wtl, 1, Hh, Hl, tmph, tmpl);
  k_stageD<<<512, 256, SM_HALF, stream>>>(tmph, tmpl, Hh, Hl, Abuf, nullptr, nullptr, 0);

  k_maps<<<NGRP, 256, 0, stream>>>(Abuf, emf, pmf, out);
}

// Round 13
// 257.407 us; speedup vs baseline: 1.0998x; 1.0998x over previous
//
#include <hip/hip_runtime.h>

#define NND   8192
#define DDIM  256
#define NGRP  32
#define ZEROF 1e-8f
#define TSTR  72   // epilogue transpose tile stride in u16
#define CCAP 192   // reorder per-(bucket,seg-chunk) capacity (mean 64, +16 sigma)
// Round-13 (= round-12 resubmit after infra failure): async global_load_lds K-loop,
// double-buffered, ONE barrier per K-step (was 2). LDS rows unpadded 32 u16
// (gload_lds writes base+lane*16B linearly); global source slot pre-swizzled by
// (row&3), read XORs it back -> 4-way bank conflict (was 8-way unswizzled).
// Buffers: HALF 2x16KB=32KB, FULL 2x24KB=48KB (round-11 lesson: keep residency).
#define SM_HALF 32768
#define SM_FULL 49152

typedef unsigned short u16;
typedef __attribute__((ext_vector_type(8))) short short8v;
typedef __attribute__((ext_vector_type(4))) float float4v;

__device__ __forceinline__ void gl16(const u16* g, u16* l) {
  __builtin_amdgcn_global_load_lds(
      (const __attribute__((address_space(1))) unsigned int*)g,
      (__attribute__((address_space(3))) unsigned int*)l, 16, 0, 0);
}

__device__ inline u16 f2bf(float x) {
  unsigned u = __float_as_uint(x);
  u += 0x7fffu + ((u >> 16) & 1u);
  return (u16)(u >> 16);
}
__device__ inline float bf2f(u16 h) { return __uint_as_float((unsigned)h << 16); }
__device__ inline void split2(float x, u16& h, u16& l) {
  h = f2bf(x);
  l = f2bf(x - bf2f(h));
}

__device__ inline float wave_sum(float v) {
#pragma unroll
  for (int off = 32; off > 0; off >>= 1) v += __shfl_down(v, off, 64);
  return v;
}

// ================= unified split-bf16 MFMA GEMM body (async dbuf) =================
// C-tile 64 x (HALF?64:128), 4 waves, 16x16x32 bf16 MFMA, split-bf16x3.
// MODE 0: XWT[c][node] = (H @ Wcat)^T       a=H(node), b=Wt(c)          [full]
// MODE 1: Hout = relu(b3 + M @ XWcat)       a=XWT(d), b=Mb h/l, K=768   [half]
// MODE 2: A_raw = x.xT (UNSCALED)           a=b=x                       [half]
// MODE 3: A = 0.5A + 0.5 sigmoid(t.HT)      a=tmp, b=H                  [half]
// MODE 5: A = 0.5*A_raw*scale + 0.5 sig(.)  a=tmp, b=H; scale=di*dj/(ni*nj+e) [half]
// MODE 4: tmp[node][d] = H @ T              a=Tt(d), b=H(node)          [half]
template<int MODE, bool HALF>
__device__ __forceinline__ void mfma_body(
    u16* lds,
    const u16* __restrict__ Ah_g, const u16* __restrict__ Al_g,
    const u16* __restrict__ Bh_g, const u16* __restrict__ Bl_g,
    float* __restrict__ Cf, u16* __restrict__ Ch, u16* __restrict__ Cl,
    const float* __restrict__ nrm, const float* __restrict__ dinv,
    const float* __restrict__ bias,
    int bxm, int bym, int g) {
  const int BS    = HALF ? 8192 : 12288;   // u16 per buffer
  const int BOFF  = 4096;                  // Bh start within buffer
  const int BLOFF = 4096 + (HALF ? 2048 : 4096);
  const int NJ = HALF ? 2 : 4;
  const int tid = threadIdx.x;
  const int col0 = bxm * (HALF ? 64 : 128);
  const int w = tid >> 6, lane = tid & 63;
  const int lm = lane & 15, lq = lane >> 4;
  const int wr = (w >> 1) * 32, wc = (w & 1) * (HALF ? 32 : 64);
  const int TOTAL = (MODE == 1) ? 24 : 8;

  const int m_ = tid >> 2;
  const int sw = ((tid & 3) ^ (m_ & 3)) * 8;   // pre-swizzled k-slot (u16)
  const int wbase = (tid >> 6) * 512;          // wave-uniform lds offset (u16)

  float4v acc[2][4];
#pragma unroll
  for (int i = 0; i < 2; ++i)
#pragma unroll
    for (int j = 0; j < NJ; ++j) acc[i][j] = (float4v)0.f;

  auto STAGE = [&](int buf, int tt, int kk) {
    u16* base = lds + buf * BS;
    size_t aoff;
    if (MODE == 1)
      aoff = (size_t)(tt * 256 + bym * 64 + m_) * 8192 + (size_t)(g * 256 + kk + sw);
    else if (MODE == 2 || MODE == 3 || MODE == 5)
      aoff = (size_t)(g * 256 + bym * 64 + m_) * 256 + kk + sw;
    else
      aoff = (size_t)(bym * 64 + m_) * 256 + kk + sw;
    gl16(&Ah_g[aoff], base + wbase);
    gl16(&Al_g[aoff], base + 2048 + wbase);
    size_t bbase = (MODE == 1) ? ((size_t)(g * 3 + tt) << 16)
                 : ((MODE == 2 || MODE == 3 || MODE == 5) ? ((size_t)g << 16) : (size_t)0);
    size_t boff = bbase + (size_t)(col0 + m_) * 256 + kk + sw;
    gl16(&Bh_g[boff], base + BOFF + wbase);
    gl16(&Bl_g[boff], base + BLOFF + wbase);
    if (!HALF) {
      size_t boff2 = boff + (size_t)64 * 256;   // rows 64..127 ((64+m)&3 == m&3 -> same sw)
      gl16(&Bh_g[boff2], base + BOFF + 2048 + wbase);
      gl16(&Bl_g[boff2], base + BLOFF + 2048 + wbase);
    }
  };

  STAGE(0, 0, 0);
  __syncthreads();                 // compiler drains vmcnt(0) before s_barrier
  int cur = 0;
  for (int step = 0; step < TOTAL; ++step) {
    int nxt = step + 1;
    if (nxt < TOTAL) {
      int tt = (MODE == 1) ? (nxt >> 3) : 0;
      int kk = (MODE == 1) ? ((nxt & 7) * 32) : (nxt * 32);
      STAGE(cur ^ 1, tt, kk);      // in flight during compute below
    }
    u16* base = lds + cur * BS;
    short8v ah[2], al[2], bh[4], bl[4];
#pragma unroll
    for (int i = 0; i < 2; ++i) {
      int r = wr + i * 16 + lm;
      int sa = (lq ^ (r & 3)) * 8;
      ah[i] = *(const short8v*)&base[r * 32 + sa];
      al[i] = *(const short8v*)&base[2048 + r * 32 + sa];
    }
#pragma unroll
    for (int j = 0; j < NJ; ++j) {
      int rb = wc + j * 16 + lm;
      int sb = (lq ^ (rb & 3)) * 8;
      bh[j] = *(const short8v*)&base[BOFF + rb * 32 + sb];
      bl[j] = *(const short8v*)&base[BLOFF + rb * 32 + sb];
    }
#pragma unroll
    for (int i = 0; i < 2; ++i)
#pragma unroll
      for (int j = 0; j < NJ; ++j) {
        acc[i][j] = __builtin_amdgcn_mfma_f32_16x16x32_bf16(ah[i], bh[j], acc[i][j], 0, 0, 0);
        acc[i][j] = __builtin_amdgcn_mfma_f32_16x16x32_bf16(ah[i], bl[j], acc[i][j], 0, 0, 0);
        acc[i][j] = __builtin_amdgcn_mfma_f32_16x16x32_bf16(al[i], bh[j], acc[i][j], 0, 0, 0);
      }
    __syncthreads();               // one barrier/step: drains reads + prefetch
    cur ^= 1;
  }

  // ---- epilogues (frag: col=lm, row=lq*4+r). Tt aliases lds (all buffers dead) ----
  u16* Tt = lds;
  if (MODE == 2 || MODE == 3 || MODE == 5) {
#pragma unroll
    for (int i = 0; i < 2; ++i) {
#pragma unroll
      for (int r = 0; r < 4; ++r) {
        int grow = g * 256 + bym * 64 + wr + i * 16 + lq * 4 + r;
        float di = 0.f, ni = 0.f;
        if (MODE == 5) { di = dinv[grow]; ni = nrm[grow]; }
#pragma unroll
        for (int j = 0; j < NJ; ++j) {
          int gcol = col0 + wc + j * 16 + lm;
          size_t ci = (size_t)grow * 256 + gcol;
          float v = acc[i][j][r];
          if (MODE == 2) {
            Cf[ci] = v;                      // RAW dot; scale deferred to MODE 5 (D-l0)
          } else if (MODE == 3) {
            Cf[ci] = 0.5f * Cf[ci] + 0.5f * (1.f / (1.f + expf(-v)));
          } else {
            int gj = g * 256 + gcol;
            float scale = di * dinv[gj] / (ni * nrm[gj] + ZEROF);
            Cf[ci] = 0.5f * Cf[ci] * scale + 0.5f * (1.f / (1.f + expf(-v)));
          }
        }
      }
    }
  } else {
    float bsum[8];
    if (MODE == 1) {
#pragma unroll
      for (int i = 0; i < 2; ++i)
#pragma unroll
        for (int r = 0; r < 4; ++r) {
          int d = bym * 64 + wr + i * 16 + lq * 4 + r;
          bsum[i * 4 + r] = bias[d] + bias[256 + d] + bias[512 + d];
        }
    }
    u16 hv[32], lv[32];
#pragma unroll
    for (int i = 0; i < 2; ++i)
#pragma unroll
      for (int j = 0; j < NJ; ++j)
#pragma unroll
        for (int r = 0; r < 4; ++r) {
          float v = acc[i][j][r];
          if (MODE == 1) v = fmaxf(v + bsum[i * 4 + r], 0.f);
          split2(v, hv[(i * 4 + r) * NJ + j], lv[(i * 4 + r) * NJ + j]);
        }
    int ebase1 = (MODE == 1) ? (g * 256 + col0) : col0;
    int ebase2 = bym * 64;
    size_t estride = (MODE == 0) ? 8192 : 256;
#pragma unroll
    for (int ph = 0; ph < 2; ++ph) {
      __syncthreads();
      const u16* sv = ph ? lv : hv;
#pragma unroll
      for (int i = 0; i < 2; ++i)
#pragma unroll
        for (int j = 0; j < NJ; ++j)
#pragma unroll
          for (int r = 0; r < 4; ++r)
            Tt[(wc + j * 16 + lm) * TSTR + wr + i * 16 + lq * 4 + r] = sv[(i * 4 + r) * NJ + j];
      __syncthreads();
      u16* dst = ph ? Cl : Ch;
      int cc0 = tid >> 3, mm0 = (tid & 7) * 8;
#pragma unroll
      for (int it = 0; it < (HALF ? 2 : 4); ++it) {
        int cc = it * 32 + cc0;
        short8v v = *(const short8v*)&Tt[cc * TSTR + mm0];
        *(short8v*)&dst[(size_t)(ebase1 + cc) * estride + ebase2 + mm0] = v;
      }
    }
  }
}

// ---- M-build block body: dense 32x256 fp32 tile from BUCKET-MAJOR records ----
__device__ __forceinline__ void mbuild_body(
    float* tile, int bid, int l,
    const uint2* __restrict__ recs2, const int* __restrict__ bcnt2,
    const float* __restrict__ Abuf, u16* __restrict__ Mbh, u16* __restrict__ Mbl) {
  const int tid = threadIdx.x;
  int gt = bid >> 3, chunk = bid & 7;
  int g = gt / 3;
  float4 z = make_float4(0.f, 0.f, 0.f, 0.f);
#pragma unroll
  for (int k = 0; k < 8; ++k) ((float4*)tile)[k * 256 + tid] = z;
  __syncthreads();
#pragma unroll
  for (int c = 0; c < 8; ++c) {
    int cnt = bcnt2[bid * 8 + c];
    const uint2* rp = &recs2[(size_t)bid * (8 * CCAP) + (size_t)c * CCAP];
    for (int k = tid; k < cnt; k += 256) {
      uint2 r = rp[k];
      int s = r.x & 255, d5 = (r.x >> 8) & 31;
      float w = l ? Abuf[(size_t)(g * 256 + s) * 256 + chunk * 32 + d5]
                  : __uint_as_float(r.y);
      atomicAdd(&tile[d5 * 256 + s], w);
    }
  }
  __syncthreads();
  size_t base4 = ((size_t)gt << 14) + ((size_t)chunk << 11);  // ushort4 units
#pragma unroll
  for (int k = 0; k < 8; ++k) {
    float4 f = ((float4*)tile)[k * 256 + tid];
    ushort4 h, lo;
    split2(f.x, h.x, lo.x); split2(f.y, h.y, lo.y);
    split2(f.z, h.z, lo.z); split2(f.w, h.w, lo.w);
    ((ushort4*)Mbh)[base4 + k * 256 + tid] = h;
    ((ushort4*)Mbl)[base4 + k * 256 + tid] = lo;
  }
}

// ===== prep: mask cvt | edge bucketing (atomic-free) | transpose/split W | norms+x-split =====
__global__ void k_prep(const int* __restrict__ e0, const int* __restrict__ e1,
                       const int* __restrict__ e2, const unsigned char* __restrict__ m0,
                       const unsigned char* __restrict__ m1,
                       const float* __restrict__ W, const float* __restrict__ T,
                       const float* __restrict__ x,
                       const float* __restrict__ ew0, const float* __restrict__ ew1,
                       const float* __restrict__ ew2,
                       float* __restrict__ emf, float* __restrict__ pmf,
                       u16* __restrict__ Wth, u16* __restrict__ Wtl,
                       u16* __restrict__ sct, uint2* __restrict__ recs,
                       float* __restrict__ nrm, float* __restrict__ Spart,
                       u16* __restrict__ Hh, u16* __restrict__ Hl,
                       int E_, int nCvt, int nBkt) {
  __shared__ float tile[32][33];
  __shared__ float inv[64];
  __shared__ int nz[1];
  __shared__ unsigned int hcnt[768];
  __shared__ unsigned int hoff[768];
  __shared__ unsigned int ppart[256];
  __shared__ uint2 stage[768];
  const int b = blockIdx.x, tid = threadIdx.x;
  if (b < nCvt) {
    // ---- mask dtype detect + convert (2*NND values) ----
    if (tid == 0) nz[0] = 0;
    __syncthreads();
    int i4 = tid * 4;
    int c = (m0[i4 + 1] != 0) + (m0[i4 + 2] != 0) + (m0[i4 + 3] != 0);
    if (c) atomicAdd(&nz[0], c);
    __syncthreads();
    int fM = (nz[0] == 0);
    int i = b * 256 + tid;
    if (i < NND) {
      unsigned char v = fM ? m0[4 * i] : m0[i];
      emf[i] = 1.f - (float)(v != 0);
    } else {
      int j = i - NND;
      unsigned char v = fM ? m1[4 * j] : m1[j];
      pmf[j] = 1.f - (float)(v != 0);
    }
  } else if (b < nCvt + nBkt) {
    // ---- atomic-free edge bucketing: block-private segments, LDS hist+scan ----
    if (tid == 0) nz[0] = 0;
    hcnt[tid] = 0; hcnt[tid + 256] = 0; hcnt[tid + 512] = 0;
    __syncthreads();
    if (e0[2 * tid + 1] != 0) atomicAdd(&nz[0], 1);
    __syncthreads();
    int fE = (nz[0] == 0);   // int64-format edges
    int e = (b - nCvt) * 256 + tid;
    bool valid = (e < E_);
    int mybid[3]; unsigned int myrec[3]; float myw[3];
    if (valid) {
#pragma unroll
      for (int t = 0; t < 3; ++t) {
        const int* ei = (t == 0) ? e0 : ((t == 1) ? e1 : e2);
        int src = fE ? ei[2 * e] : ei[e];
        int dst = fE ? ei[2 * (E_ + e)] : ei[E_ + e];
        int g = src >> 8, s = src & 255, d = dst & 255;
        mybid[t] = ((g * 3 + t) << 3) | (d >> 5);
        myrec[t] = (unsigned)(((d & 31) << 8) | s);
        myw[t] = (t == 0 ? ew0 : (t == 1 ? ew1 : ew2))[e];
        atomicAdd(&hcnt[mybid[t]], 1u);
      }
    }
    __syncthreads();
    unsigned c0 = hcnt[3 * tid], c1 = hcnt[3 * tid + 1], c2 = hcnt[3 * tid + 2];
    unsigned tsum = c0 + c1 + c2;
    ppart[tid] = tsum;
    __syncthreads();
    for (int off = 1; off < 256; off <<= 1) {
      unsigned v = (tid >= off) ? ppart[tid - off] : 0u;
      __syncthreads();
      ppart[tid] += v;
      __syncthreads();
    }
    unsigned base = ppart[tid] - tsum;   // exclusive prefix
    hoff[3 * tid] = base;
    hoff[3 * tid + 1] = base + c0;
    hoff[3 * tid + 2] = base + c0 + c1;
    __syncthreads();
#pragma unroll
    for (int k = 0; k < 3; ++k) {
      int bin = tid + k * 256;
      unsigned cc = hcnt[bin]; if (cc > 31u) cc = 31u;
      sct[(size_t)(b - nCvt) * 768 + bin] = (u16)(hoff[bin] | (cc << 11));
    }
    __syncthreads();
    if (valid) {
#pragma unroll
      for (int t = 0; t < 3; ++t) {
        unsigned slot = atomicAdd(&hoff[mybid[t]], 1u);
        stage[slot] = make_uint2(myrec[t], __float_as_uint(myw[t]));
      }
    }
    __syncthreads();
    uint2* dstp = &recs[(size_t)(b - nCvt) * 768];
    dstp[tid] = stage[tid];
    dstp[tid + 256] = stage[tid + 256];
    dstp[tid + 512] = stage[tid + 512];
  } else if (b < nCvt + nBkt + 512) {
    int bb = b - nCvt - nBkt;
    int mat = bb >> 6, rem = bb & 63;
    int k0 = (rem >> 3) * 32, n0 = (rem & 7) * 32;
    const float* src = (mat < 6) ? (W + (size_t)mat * 65536) : (T + (size_t)(mat - 6) * 65536);
    int r = tid >> 3, c4 = (tid & 7) * 4;
    const float4 v = *(const float4*)&src[(size_t)(k0 + r) * 256 + n0 + c4];
    tile[r][c4 + 0] = v.x; tile[r][c4 + 1] = v.y; tile[r][c4 + 2] = v.z; tile[r][c4 + 3] = v.w;
    __syncthreads();
    float o[4] = {tile[c4 + 0][r], tile[c4 + 1][r], tile[c4 + 2][r], tile[c4 + 3][r]};
    u16 hh[4], ll[4];
#pragma unroll
    for (int q = 0; q < 4; ++q) split2(o[q], hh[q], ll[q]);
    size_t off = (size_t)mat * 65536 + (size_t)(n0 + r) * 256 + k0 + c4;
    *(ushort4*)&Wth[off] = *(ushort4*)hh;
    *(ushort4*)&Wtl[off] = *(ushort4*)ll;
  } else {
    int bn = b - nCvt - nBkt - 512;    // 0..127
    int n0 = bn * 64;
    int w = tid >> 6, lane = tid & 63;
    for (int it = 0; it < 16; ++it) {
      int nl = it * 4 + w;
      int node = n0 + nl;
      const float4 v = *(const float4*)&x[(size_t)node * 256 + lane * 4];
      u16 hh[4], ll[4];
      split2(v.x, hh[0], ll[0]); split2(v.y, hh[1], ll[1]);
      split2(v.z, hh[2], ll[2]); split2(v.w, hh[3], ll[3]);
      *(ushort4*)&Hh[(size_t)node * 256 + lane * 4] = *(ushort4*)hh;
      *(ushort4*)&Hl[(size_t)node * 256 + lane * 4] = *(ushort4*)ll;
      float s = wave_sum(v.x * v.x + v.y * v.y + v.z * v.z + v.w * v.w);
      if (lane == 0) { float nr = sqrtf(s); nrm[node] = nr; inv[nl] = 1.f / nr; }
    }
    __syncthreads();
    float s = 0.f;
    for (int i = 0; i < 64; ++i) s += x[(size_t)(n0 + i) * 256 + tid] * inv[i];
    Spart[bn * 256 + tid] = s;
  }
}

// ==== k_reorder: WAVE per (bucket,chunk); lane i owns segment i; shfl prefix-sum ====
__global__ void k_reorder(const u16* __restrict__ sct, const uint2* __restrict__ recs,
                          uint2* __restrict__ recs2, int* __restrict__ bcnt2, int nBkt) {
  const int wid = blockIdx.x * 4 + (threadIdx.x >> 6);  // 0..6143
  const int lane = threadIdx.x & 63;
  const int bid = wid >> 3;       // bucket 0..767
  const int c = wid & 7;          // chunk 0..7
  const int nseg = nBkt >> 3;     // 64 for E=131072
  unsigned cnt = 0, start = 0;
  int bb = c * nseg + lane;
  if (lane < nseg) {
    unsigned sc = sct[(size_t)bb * 768 + bid];
    start = sc & 2047u; cnt = sc >> 11;
  }
  unsigned pre = cnt;
#pragma unroll
  for (int off = 1; off < 64; off <<= 1) {
    unsigned v = __shfl_up(pre, off, 64);
    if (lane >= off) pre += v;
  }
  unsigned excl = pre - cnt;
  unsigned total = __shfl(pre, 63, 64);
  uint2* dst = &recs2[(size_t)bid * (8 * CCAP) + (size_t)c * CCAP];
  const uint2* rp = &recs[(size_t)bb * 768 + start];
  for (unsigned k = 0; k < cnt; ++k) {
    unsigned o = excl + k;
    if (o < CCAP) dst[o] = rp[k];
  }
  if (lane == 0) bcnt2[bid * 8 + c] = (total > CCAP) ? CCAP : total;
}

// ==== stage A (l0, max heterogeneous pack):
//  mode0 GEMM l0 (768) | M-build l0 (768) | mode2 RAW x.xT (512) | dinv (128) ====
__global__ __launch_bounds__(256, 2) void k_stageA(
    const u16* __restrict__ Hinh, const u16* __restrict__ Hinl,
    const u16* __restrict__ Wth, const u16* __restrict__ Wtl,
    u16* __restrict__ XWTh, u16* __restrict__ XWTl,
    const uint2* __restrict__ recs2, const int* __restrict__ bcnt2,
    u16* __restrict__ Mbh, u16* __restrict__ Mbl,
    float* __restrict__ Abuf,
    const float* __restrict__ x, const float* __restrict__ Spart,
    const float* __restrict__ nrm, float* __restrict__ dinv) {
  extern __shared__ u16 lds[];
  const int b = blockIdx.x;
  if (b < 768) {
    mfma_body<0, false>(lds, Hinh, Hinl, Wth, Wtl,
                        nullptr, XWTh, XWTl, nullptr, nullptr, nullptr,
                        b >> 7, b & 127, 0);
  } else if (b < 1536) {
    mbuild_body((float*)lds, b - 768, 0, recs2, bcnt2, nullptr, Mbh, Mbl);
  } else if (b < 2048) {
    int bb = b - 1536;
    int g = bb & 31, r = bb >> 5;      // r: 0..15 -> bxm 0..3, bym 0..3
    mfma_body<2, true>(lds, Hinh, Hinl, Hinh, Hinl, Abuf, nullptr, nullptr,
                       nullptr, nullptr, nullptr, r >> 2, r & 3, g);
  } else {
    float* Sl = (float*)lds;
    const int tid = threadIdx.x;
    float s = 0.f;
    for (int bb = 0; bb < 128; ++bb) s += Spart[bb * 256 + tid];
    Sl[tid] = s;
    __syncthreads();
    int base = (b - 2048) * 64;
    int w = tid >> 6, lane = tid & 63;
    const float4 sv = *(const float4*)&Sl[lane * 4];
    for (int it = 0; it < 16; ++it) {
      int node = base + it * 4 + w;
      const float4 v = *(const float4*)&x[(size_t)node * 256 + lane * 4];
      float s2 = wave_sum(v.x * sv.x + v.y * sv.y + v.z * sv.z + v.w * sv.w);
      if (lane == 0) {
        float rowsum = s2 / nrm[node];
        dinv[node] = rsqrtf(fabsf(rowsum) + ZEROF);
      }
    }
  }
}

// ==== stage A2 (l1, fused heterogeneous pack): mode0 GEMM l1 (768) | M-build l1 (768) ====
__global__ __launch_bounds__(256, 2) void k_stageA2(
    const u16* __restrict__ H2h, const u16* __restrict__ H2l,
    const u16* __restrict__ Wth, const u16* __restrict__ Wtl,
    u16* __restrict__ XWTh, u16* __restrict__ XWTl,
    const uint2* __restrict__ recs2, const int* __restrict__ bcnt2,
    const float* __restrict__ Abuf,
    u16* __restrict__ Mbh, u16* __restrict__ Mbl) {
  extern __shared__ u16 lds[];
  const int b = blockIdx.x;
  if (b < 768) {
    mfma_body<0, false>(lds, H2h, H2l, Wth + (size_t)768 * 256, Wtl + (size_t)768 * 256,
                        nullptr, XWTh, XWTl, nullptr, nullptr, nullptr,
                        b >> 7, b & 127, 0);
  } else {
    mbuild_body((float*)lds, b - 768, 1, recs2, bcnt2, Abuf, Mbh, Mbl);
  }
}

// ==== stage B: mode1 only (HALF 64x64, 512 blocks) ====
__global__ __launch_bounds__(256, 2) void k_stageB(
    const u16* __restrict__ XWTh, const u16* __restrict__ XWTl,
    const u16* __restrict__ Mbh, const u16* __restrict__ Mbl,
    u16* __restrict__ Houth, u16* __restrict__ Houtl, const float* __restrict__ bias) {
  extern __shared__ u16 lds[];
  const int b = blockIdx.x;
  int g = b & 31, r = b >> 5;          // r: 0..15 -> bxm 0..3, bym 0..3
  mfma_body<1, true>(lds, XWTh, XWTl, Mbh, Mbl,
                     nullptr, Houth, Houtl, nullptr, nullptr, bias,
                     r >> 2, r & 3, g);
}

// ============ stage C: mode4 (half, 512): tmp = H @ T ============
__global__ __launch_bounds__(256, 2) void k_stageC(
    const u16* __restrict__ Wth, const u16* __restrict__ Wtl, int l,
    const u16* __restrict__ Hh, const u16* __restrict__ Hl,
    u16* __restrict__ tmph, u16* __restrict__ tmpl) {
  extern __shared__ u16 lds[];
  const int b = blockIdx.x;
  mfma_body<4, true>(lds, Wth + (size_t)(6 + l) * 65536, Wtl + (size_t)(6 + l) * 65536,
                     Hh, Hl, nullptr, tmph, tmpl, nullptr, nullptr, nullptr,
                     b & 127, b >> 7, 0);
}

// ============ stage D: A update. scaled!=0 (l0): MODE 5 applies the deferred scale ============
__global__ __launch_bounds__(256, 2) void k_stageD(
    const u16* __restrict__ tmph, const u16* __restrict__ tmpl,
    const u16* __restrict__ Hh, const u16* __restrict__ Hl,
    float* __restrict__ Abuf,
    const float* __restrict__ nrm, const float* __restrict__ dinv, int scaled) {
  extern __shared__ u16 lds[];
  const int b = blockIdx.x;
  int g = b & 31, r = b >> 5;
  if (scaled)
    mfma_body<5, true>(lds, tmph, tmpl, Hh, Hl, Abuf, nullptr, nullptr,
                       nrm, dinv, nullptr, r >> 2, r & 3, g);
  else
    mfma_body<3, true>(lds, tmph, tmpl, Hh, Hl, Abuf, nullptr, nullptr,
                       nullptr, nullptr, nullptr, r >> 2, r & 3, g);
}

// ============ fused maps ============
__global__ void k_maps(const float* __restrict__ Abuf, const float* __restrict__ emf,
                       const float* __restrict__ pmf, float* __restrict__ out) {
  __shared__ float sme[256], smp[256], red[256];
  const int g = blockIdx.x, tid = threadIdx.x, w = tid >> 6, lane = tid & 63;
  const int j0 = g * 256 + lane * 4;
  const float4 pmv = *(const float4*)&pmf[j0];
  const float4 emv = *(const float4*)&emf[j0];
  for (int it = 0; it < 64; ++it) {
    int nl = it * 4 + w;
    const float4 a = *(const float4*)&Abuf[((size_t)g * 256 + nl) * 256 + lane * 4];
    float me = a.x * pmv.x + a.y * pmv.y + a.z * pmv.z + a.w * pmv.w;
    float mp = a.x * emv.x + a.y * emv.y + a.z * emv.z + a.w * emv.w;
#pragma unroll
    for (int off = 32; off > 0; off >>= 1) {
      me += __shfl_down(me, off, 64);
      mp += __shfl_down(mp, off, 64);
    }
    if (lane == 0) { sme[nl] = me; smp[nl] = mp; }
  }
  __syncthreads();
  for (int which = 0; which < 2; ++which) {
    float v = which ? smp[tid] : sme[tid];
    red[tid] = v; __syncthreads();
    for (int s = 128; s > 0; s >>= 1) { if (tid < s) red[tid] = fminf(red[tid], red[tid + s]); __syncthreads(); }
    float mn = red[0]; __syncthreads();
    red[tid] = v; __syncthreads();
    for (int s = 128; s > 0; s >>= 1) { if (tid < s) red[tid] = fmaxf(red[tid], red[tid + s]); __syncthreads(); }
    float mx = red[0]; __syncthreads();
    float m = (v - mn) / (mx - mn + ZEROF);
    red[tid] = m; __syncthreads();
    for (int s = 128; s > 0; s >>= 1) { if (tid < s) red[tid] += red[tid + s]; __syncthreads(); }
    float sum = red[0]; __syncthreads();
    out[which * NND + g * 256 + tid] = m / (sum + ZEROF);
  }
}

// ================= launch =================
extern "C" void kernel_launch(void* const* d_in, const int* in_sizes, int n_in,
                              void* d_out, int out_size, void* d_ws, size_t ws_size,
                              hipStream_t stream) {
  const float* x = (const float*)d_in[0];
  const unsigned char* em_raw = (const unsigned char*)d_in[7];
  const unsigned char* pm_raw = (const unsigned char*)d_in[8];
  const float* W  = (const float*)d_in[9];
  const float* bg = (const float*)d_in[10];
  const float* T  = (const float*)d_in[11];
  float* out = (float*)d_out;
  const int E_ = in_sizes[2];

  const int nCvt = (2 * NND) / 256;          // 64
  const int nBkt = (E_ + 255) / 256;         // 512 for E=131072

  float* ws = (float*)d_ws;
  size_t o = 0;
  float* Abuf = ws + o; o += (size_t)NND * 256;
  u16* Mbh_l0 = (u16*)(ws + o); o += (size_t)NGRP * 3 * 65536 / 2;
  u16* Mbl_l0 = (u16*)(ws + o); o += (size_t)NGRP * 3 * 65536 / 2;
  u16* Mbh_l1 = (u16*)(ws + o); o += (size_t)NGRP * 3 * 65536 / 2;
  u16* Mbl_l1 = (u16*)(ws + o); o += (size_t)NGRP * 3 * 65536 / 2;
  u16* Hh   = (u16*)(ws + o); o += (size_t)NND * 256 / 2;
  u16* Hl   = (u16*)(ws + o); o += (size_t)NND * 256 / 2;
  u16* H2h  = (u16*)(ws + o); o += (size_t)NND * 256 / 2;
  u16* H2l  = (u16*)(ws + o); o += (size_t)NND * 256 / 2;
  u16* tmph = (u16*)(ws + o); o += (size_t)NND * 256 / 2;
  u16* tmpl = (u16*)(ws + o); o += (size_t)NND * 256 / 2;
  u16* XWTh = (u16*)(ws + o); o += (size_t)768 * NND / 2;
  u16* XWTl = (u16*)(ws + o); o += (size_t)768 * NND / 2;
  u16* Wth  = (u16*)(ws + o); o += (size_t)8 * 65536 / 2;
  u16* Wtl  = (u16*)(ws + o); o += (size_t)8 * 65536 / 2;
  float* nrm   = ws + o; o += NND;
  float* dinv  = ws + o; o += NND;
  float* Spart = ws + o; o += 128 * 256;
  float* emf   = ws + o; o += NND;
  float* pmf   = ws + o; o += NND;
  u16* sct     = (u16*)(ws + o); o += (size_t)nBkt * 768 / 2;
  uint2* recs  = (uint2*)(ws + o); o += (size_t)nBkt * 768 * 2;
  uint2* recs2 = (uint2*)(ws + o); o += (size_t)768 * 8 * CCAP * 2;
  int* bcnt2   = (int*)(ws + o); o += (size_t)768 * 8;

  const float* ew0 = (const float*)d_in[2];
  const float* ew1 = (const float*)d_in[4];
  const float* ew2 = (const float*)d_in[6];

  k_prep<<<nCvt + nBkt + 512 + 128, 256, 0, stream>>>(
      (const int*)d_in[1], (const int*)d_in[3], (const int*)d_in[5], em_raw, pm_raw,
      W, T, x, ew0, ew1, ew2, emf, pmf, Wth, Wtl, sct, recs,
      nrm, Spart, Hh, Hl, E_, nCvt, nBkt);

  k_reorder<<<1536, 256, 0, stream>>>(sct, recs, recs2, bcnt2, nBkt);

  // ---- layer 0 ----
  k_stageA<<<2176, 256, SM_FULL, stream>>>(Hh, Hl, Wth, Wtl, XWTh, XWTl,
                                           recs2, bcnt2, Mbh_l0, Mbl_l0, Abuf,
                                           x, Spart, nrm, dinv);
  k_stageB<<<512, 256, SM_HALF, stream>>>(XWTh, XWTl, Mbh_l0, Mbl_l0, H2h, H2l, bg);
  k_stageC<<<512, 256, SM_HALF, stream>>>(Wth, Wtl, 0, H2h, H2l, tmph, tmpl);
  k_stageD<<<512, 256, SM_HALF, stream>>>(tmph, tmpl, H2h, H2l, Abuf, nrm, dinv, 1);

  // ---- layer 1 ----
  k_stageA2<<<1536, 256, SM_FULL, stream>>>(H2h, H2l, Wth, Wtl, XWTh, XWTl,
                                            recs2, bcnt2, Abuf, Mbh_l1, Mbl_l1);
  k_stageB<<<512, 256, SM_HALF, stream>>>(XWTh, XWTl, Mbh_l1, Mbl_l1, Hh, Hl, bg + 768);
  k_stageC<<<512, 256, SM_HALF, stream>>>(Wth, Wtl, 1, Hh, Hl, tmph, tmpl);
  k_stageD<<<512, 256, SM_HALF, stream>>>(tmph, tmpl, Hh, Hl, Abuf, nullptr, nullptr, 0);

  k_maps<<<NGRP, 256, 0, stream>>>(Abuf, emf, pmf, out);
}

// Round 14
// 253.736 us; speedup vs baseline: 1.1157x; 1.0145x over previous
//
#include <hip/hip_runtime.h>

#define NND   8192
#define DDIM  256
#define NGRP  32
#define ZEROF 1e-8f
#define TSTR  72   // epilogue transpose tile stride in u16
#define CCAP 192   // reorder per-(bucket,seg-chunk) capacity (mean 64, +16 sigma)
// Round-14: counted-vmcnt pipeline (guide T3/T4 minimum recipe). Per K-step:
// STAGE(N+1) [L loads] -> s_waitcnt vmcnt(L) [own STAGE(N) landed] -> raw s_barrier
// [all waves' buf-N landed] -> compute -> raw s_barrier [buf N safe to overwrite].
// No vmcnt(0) drain in the loop (round-13's __syncthreads drained the prefetch
// every step). Buffers: HALF 2x16KB=32KB, FULL 2x24KB=48KB (unchanged).
#define SM_HALF 32768
#define SM_FULL 49152

typedef unsigned short u16;
typedef __attribute__((ext_vector_type(8))) short short8v;
typedef __attribute__((ext_vector_type(4))) float float4v;

__device__ __forceinline__ void gl16(const u16* g, u16* l) {
  __builtin_amdgcn_global_load_lds(
      (const __attribute__((address_space(1))) unsigned int*)g,
      (__attribute__((address_space(3))) unsigned int*)l, 16, 0, 0);
}

template<int N>
__device__ __forceinline__ void waitv() {
  if constexpr (N == 0)      asm volatile("s_waitcnt vmcnt(0)" ::: "memory");
  else if constexpr (N == 4) asm volatile("s_waitcnt vmcnt(4)" ::: "memory");
  else                       asm volatile("s_waitcnt vmcnt(6)" ::: "memory");
}

__device__ inline u16 f2bf(float x) {
  unsigned u = __float_as_uint(x);
  u += 0x7fffu + ((u >> 16) & 1u);
  return (u16)(u >> 16);
}
__device__ inline float bf2f(u16 h) { return __uint_as_float((unsigned)h << 16); }
__device__ inline void split2(float x, u16& h, u16& l) {
  h = f2bf(x);
  l = f2bf(x - bf2f(h));
}

__device__ inline float wave_sum(float v) {
#pragma unroll
  for (int off = 32; off > 0; off >>= 1) v += __shfl_down(v, off, 64);
  return v;
}

// ================= unified split-bf16 MFMA GEMM body (async dbuf, counted vmcnt) =================
// C-tile 64 x (HALF?64:128), 4 waves, 16x16x32 bf16 MFMA, split-bf16x3.
// MODE 0: XWT[c][node] = (H @ Wcat)^T       a=H(node), b=Wt(c)          [full]
// MODE 1: Hout = relu(b3 + M @ XWcat)       a=XWT(d), b=Mb h/l, K=768   [half]
// MODE 2: A_raw = x.xT (UNSCALED)           a=b=x                       [half]
// MODE 3: A = 0.5A + 0.5 sigmoid(t.HT)      a=tmp, b=H                  [half]
// MODE 5: A = 0.5*A_raw*scale + 0.5 sig(.)  a=tmp, b=H; scale=di*dj/(ni*nj+e) [half]
// MODE 4: tmp[node][d] = H @ T              a=Tt(d), b=H(node)          [half]
template<int MODE, bool HALF>
__device__ __forceinline__ void mfma_body(
    u16* lds,
    const u16* __restrict__ Ah_g, const u16* __restrict__ Al_g,
    const u16* __restrict__ Bh_g, const u16* __restrict__ Bl_g,
    float* __restrict__ Cf, u16* __restrict__ Ch, u16* __restrict__ Cl,
    const float* __restrict__ nrm, const float* __restrict__ dinv,
    const float* __restrict__ bias,
    int bxm, int bym, int g) {
  const int BS    = HALF ? 8192 : 12288;   // u16 per buffer
  const int BOFF  = 4096;                  // Bh start within buffer
  const int BLOFF = 4096 + (HALF ? 2048 : 4096);
  const int NJ = HALF ? 2 : 4;
  const int NLD = HALF ? 4 : 6;            // gl16 per STAGE
  const int tid = threadIdx.x;
  const int col0 = bxm * (HALF ? 64 : 128);
  const int w = tid >> 6, lane = tid & 63;
  const int lm = lane & 15, lq = lane >> 4;
  const int wr = (w >> 1) * 32, wc = (w & 1) * (HALF ? 32 : 64);
  const int TOTAL = (MODE == 1) ? 24 : 8;

  const int m_ = tid >> 2;
  const int sw = ((tid & 3) ^ (m_ & 3)) * 8;   // pre-swizzled k-slot (u16)
  const int wbase = (tid >> 6) * 512;          // wave-uniform lds offset (u16)

  float4v acc[2][4];
#pragma unroll
  for (int i = 0; i < 2; ++i)
#pragma unroll
    for (int j = 0; j < NJ; ++j) acc[i][j] = (float4v)0.f;

  auto STAGE = [&](int buf, int tt, int kk) {
    u16* base = lds + buf * BS;
    size_t aoff;
    if (MODE == 1)
      aoff = (size_t)(tt * 256 + bym * 64 + m_) * 8192 + (size_t)(g * 256 + kk + sw);
    else if (MODE == 2 || MODE == 3 || MODE == 5)
      aoff = (size_t)(g * 256 + bym * 64 + m_) * 256 + kk + sw;
    else
      aoff = (size_t)(bym * 64 + m_) * 256 + kk + sw;
    gl16(&Ah_g[aoff], base + wbase);
    gl16(&Al_g[aoff], base + 2048 + wbase);
    size_t bbase = (MODE == 1) ? ((size_t)(g * 3 + tt) << 16)
                 : ((MODE == 2 || MODE == 3 || MODE == 5) ? ((size_t)g << 16) : (size_t)0);
    size_t boff = bbase + (size_t)(col0 + m_) * 256 + kk + sw;
    gl16(&Bh_g[boff], base + BOFF + wbase);
    gl16(&Bl_g[boff], base + BLOFF + wbase);
    if (!HALF) {
      size_t boff2 = boff + (size_t)64 * 256;   // rows 64..127 ((64+m)&3 == m&3 -> same sw)
      gl16(&Bh_g[boff2], base + BOFF + 2048 + wbase);
      gl16(&Bl_g[boff2], base + BLOFF + 2048 + wbase);
    }
  };

  STAGE(0, 0, 0);
  waitv<0>();
  __builtin_amdgcn_s_barrier();
  __builtin_amdgcn_sched_barrier(0);
  int cur = 0;
  for (int step = 0; step < TOTAL; ++step) {
    int nxt = step + 1;
    if (nxt < TOTAL) {
      int tt = (MODE == 1) ? (nxt >> 3) : 0;
      int kk = (MODE == 1) ? ((nxt & 7) * 32) : (nxt * 32);
      STAGE(cur ^ 1, tt, kk);      // in flight across barriers below
      waitv<NLD>();                // own STAGE(step) landed; prefetch stays outstanding
    } else {
      waitv<0>();                  // final step: drain everything
    }
    __builtin_amdgcn_s_barrier();  // all waves' buf-cur data landed
    __builtin_amdgcn_sched_barrier(0);
    u16* base = lds + cur * BS;
    short8v ah[2], al[2], bh[4], bl[4];
#pragma unroll
    for (int i = 0; i < 2; ++i) {
      int r = wr + i * 16 + lm;
      int sa = (lq ^ (r & 3)) * 8;
      ah[i] = *(const short8v*)&base[r * 32 + sa];
      al[i] = *(const short8v*)&base[2048 + r * 32 + sa];
    }
#pragma unroll
    for (int j = 0; j < NJ; ++j) {
      int rb = wc + j * 16 + lm;
      int sb = (lq ^ (rb & 3)) * 8;
      bh[j] = *(const short8v*)&base[BOFF + rb * 32 + sb];
      bl[j] = *(const short8v*)&base[BLOFF + rb * 32 + sb];
    }
#pragma unroll
    for (int i = 0; i < 2; ++i)
#pragma unroll
      for (int j = 0; j < NJ; ++j) {
        acc[i][j] = __builtin_amdgcn_mfma_f32_16x16x32_bf16(ah[i], bh[j], acc[i][j], 0, 0, 0);
        acc[i][j] = __builtin_amdgcn_mfma_f32_16x16x32_bf16(ah[i], bl[j], acc[i][j], 0, 0, 0);
        acc[i][j] = __builtin_amdgcn_mfma_f32_16x16x32_bf16(al[i], bh[j], acc[i][j], 0, 0, 0);
      }
    __builtin_amdgcn_s_barrier();  // all waves done reading buf cur -> next STAGE may overwrite
    cur ^= 1;
  }

  // ---- epilogues (frag: col=lm, row=lq*4+r). Tt aliases lds (all buffers drained) ----
  u16* Tt = lds;
  if (MODE == 2 || MODE == 3 || MODE == 5) {
#pragma unroll
    for (int i = 0; i < 2; ++i) {
#pragma unroll
      for (int r = 0; r < 4; ++r) {
        int grow = g * 256 + bym * 64 + wr + i * 16 + lq * 4 + r;
        float di = 0.f, ni = 0.f;
        if (MODE == 5) { di = dinv[grow]; ni = nrm[grow]; }
#pragma unroll
        for (int j = 0; j < NJ; ++j) {
          int gcol = col0 + wc + j * 16 + lm;
          size_t ci = (size_t)grow * 256 + gcol;
          float v = acc[i][j][r];
          if (MODE == 2) {
            Cf[ci] = v;                      // RAW dot; scale deferred to MODE 5 (D-l0)
          } else if (MODE == 3) {
            Cf[ci] = 0.5f * Cf[ci] + 0.5f * (1.f / (1.f + expf(-v)));
          } else {
            int gj = g * 256 + gcol;
            float scale = di * dinv[gj] / (ni * nrm[gj] + ZEROF);
            Cf[ci] = 0.5f * Cf[ci] * scale + 0.5f * (1.f / (1.f + expf(-v)));
          }
        }
      }
    }
  } else {
    float bsum[8];
    if (MODE == 1) {
#pragma unroll
      for (int i = 0; i < 2; ++i)
#pragma unroll
        for (int r = 0; r < 4; ++r) {
          int d = bym * 64 + wr + i * 16 + lq * 4 + r;
          bsum[i * 4 + r] = bias[d] + bias[256 + d] + bias[512 + d];
        }
    }
    u16 hv[32], lv[32];
#pragma unroll
    for (int i = 0; i < 2; ++i)
#pragma unroll
      for (int j = 0; j < NJ; ++j)
#pragma unroll
        for (int r = 0; r < 4; ++r) {
          float v = acc[i][j][r];
          if (MODE == 1) v = fmaxf(v + bsum[i * 4 + r], 0.f);
          split2(v, hv[(i * 4 + r) * NJ + j], lv[(i * 4 + r) * NJ + j]);
        }
    int ebase1 = (MODE == 1) ? (g * 256 + col0) : col0;
    int ebase2 = bym * 64;
    size_t estride = (MODE == 0) ? 8192 : 256;
#pragma unroll
    for (int ph = 0; ph < 2; ++ph) {
      __syncthreads();
      const u16* sv = ph ? lv : hv;
#pragma unroll
      for (int i = 0; i < 2; ++i)
#pragma unroll
        for (int j = 0; j < NJ; ++j)
#pragma unroll
          for (int r = 0; r < 4; ++r)
            Tt[(wc + j * 16 + lm) * TSTR + wr + i * 16 + lq * 4 + r] = sv[(i * 4 + r) * NJ + j];
      __syncthreads();
      u16* dst = ph ? Cl : Ch;
      int cc0 = tid >> 3, mm0 = (tid & 7) * 8;
#pragma unroll
      for (int it = 0; it < (HALF ? 2 : 4); ++it) {
        int cc = it * 32 + cc0;
        short8v v = *(const short8v*)&Tt[cc * TSTR + mm0];
        *(short8v*)&dst[(size_t)(ebase1 + cc) * estride + ebase2 + mm0] = v;
      }
    }
  }
}

// ---- M-build block body: dense 32x256 fp32 tile from BUCKET-MAJOR records ----
__device__ __forceinline__ void mbuild_body(
    float* tile, int bid, int l,
    const uint2* __restrict__ recs2, const int* __restrict__ bcnt2,
    const float* __restrict__ Abuf, u16* __restrict__ Mbh, u16* __restrict__ Mbl) {
  const int tid = threadIdx.x;
  int gt = bid >> 3, chunk = bid & 7;
  int g = gt / 3;
  float4 z = make_float4(0.f, 0.f, 0.f, 0.f);
#pragma unroll
  for (int k = 0; k < 8; ++k) ((float4*)tile)[k * 256 + tid] = z;
  __syncthreads();
#pragma unroll
  for (int c = 0; c < 8; ++c) {
    int cnt = bcnt2[bid * 8 + c];
    const uint2* rp = &recs2[(size_t)bid * (8 * CCAP) + (size_t)c * CCAP];
    for (int k = tid; k < cnt; k += 256) {
      uint2 r = rp[k];
      int s = r.x & 255, d5 = (r.x >> 8) & 31;
      float w = l ? Abuf[(size_t)(g * 256 + s) * 256 + chunk * 32 + d5]
                  : __uint_as_float(r.y);
      atomicAdd(&tile[d5 * 256 + s], w);
    }
  }
  __syncthreads();
  size_t base4 = ((size_t)gt << 14) + ((size_t)chunk << 11);  // ushort4 units
#pragma unroll
  for (int k = 0; k < 8; ++k) {
    float4 f = ((float4*)tile)[k * 256 + tid];
    ushort4 h, lo;
    split2(f.x, h.x, lo.x); split2(f.y, h.y, lo.y);
    split2(f.z, h.z, lo.z); split2(f.w, h.w, lo.w);
    ((ushort4*)Mbh)[base4 + k * 256 + tid] = h;
    ((ushort4*)Mbl)[base4 + k * 256 + tid] = lo;
  }
}

// ===== prep: mask cvt | edge bucketing (atomic-free) | transpose/split W | norms+x-split =====
__global__ void k_prep(const int* __restrict__ e0, const int* __restrict__ e1,
                       const int* __restrict__ e2, const unsigned char* __restrict__ m0,
                       const unsigned char* __restrict__ m1,
                       const float* __restrict__ W, const float* __restrict__ T,
                       const float* __restrict__ x,
                       const float* __restrict__ ew0, const float* __restrict__ ew1,
                       const float* __restrict__ ew2,
                       float* __restrict__ emf, float* __restrict__ pmf,
                       u16* __restrict__ Wth, u16* __restrict__ Wtl,
                       u16* __restrict__ sct, uint2* __restrict__ recs,
                       float* __restrict__ nrm, float* __restrict__ Spart,
                       u16* __restrict__ Hh, u16* __restrict__ Hl,
                       int E_, int nCvt, int nBkt) {
  __shared__ float tile[32][33];
  __shared__ float inv[64];
  __shared__ int nz[1];
  __shared__ unsigned int hcnt[768];
  __shared__ unsigned int hoff[768];
  __shared__ unsigned int ppart[256];
  __shared__ uint2 stage[768];
  const int b = blockIdx.x, tid = threadIdx.x;
  if (b < nCvt) {
    // ---- mask dtype detect + convert (2*NND values) ----
    if (tid == 0) nz[0] = 0;
    __syncthreads();
    int i4 = tid * 4;
    int c = (m0[i4 + 1] != 0) + (m0[i4 + 2] != 0) + (m0[i4 + 3] != 0);
    if (c) atomicAdd(&nz[0], c);
    __syncthreads();
    int fM = (nz[0] == 0);
    int i = b * 256 + tid;
    if (i < NND) {
      unsigned char v = fM ? m0[4 * i] : m0[i];
      emf[i] = 1.f - (float)(v != 0);
    } else {
      int j = i - NND;
      unsigned char v = fM ? m1[4 * j] : m1[j];
      pmf[j] = 1.f - (float)(v != 0);
    }
  } else if (b < nCvt + nBkt) {
    // ---- atomic-free edge bucketing: block-private segments, LDS hist+scan ----
    if (tid == 0) nz[0] = 0;
    hcnt[tid] = 0; hcnt[tid + 256] = 0; hcnt[tid + 512] = 0;
    __syncthreads();
    if (e0[2 * tid + 1] != 0) atomicAdd(&nz[0], 1);
    __syncthreads();
    int fE = (nz[0] == 0);   // int64-format edges
    int e = (b - nCvt) * 256 + tid;
    bool valid = (e < E_);
    int mybid[3]; unsigned int myrec[3]; float myw[3];
    if (valid) {
#pragma unroll
      for (int t = 0; t < 3; ++t) {
        const int* ei = (t == 0) ? e0 : ((t == 1) ? e1 : e2);
        int src = fE ? ei[2 * e] : ei[e];
        int dst = fE ? ei[2 * (E_ + e)] : ei[E_ + e];
        int g = src >> 8, s = src & 255, d = dst & 255;
        mybid[t] = ((g * 3 + t) << 3) | (d >> 5);
        myrec[t] = (unsigned)(((d & 31) << 8) | s);
        myw[t] = (t == 0 ? ew0 : (t == 1 ? ew1 : ew2))[e];
        atomicAdd(&hcnt[mybid[t]], 1u);
      }
    }
    __syncthreads();
    unsigned c0 = hcnt[3 * tid], c1 = hcnt[3 * tid + 1], c2 = hcnt[3 * tid + 2];
    unsigned tsum = c0 + c1 + c2;
    ppart[tid] = tsum;
    __syncthreads();
    for (int off = 1; off < 256; off <<= 1) {
      unsigned v = (tid >= off) ? ppart[tid - off] : 0u;
      __syncthreads();
      ppart[tid] += v;
      __syncthreads();
    }
    unsigned base = ppart[tid] - tsum;   // exclusive prefix
    hoff[3 * tid] = base;
    hoff[3 * tid + 1] = base + c0;
    hoff[3 * tid + 2] = base + c0 + c1;
    __syncthreads();
#pragma unroll
    for (int k = 0; k < 3; ++k) {
      int bin = tid + k * 256;
      unsigned cc = hcnt[bin]; if (cc > 31u) cc = 31u;
      sct[(size_t)(b - nCvt) * 768 + bin] = (u16)(hoff[bin] | (cc << 11));
    }
    __syncthreads();
    if (valid) {
#pragma unroll
      for (int t = 0; t < 3; ++t) {
        unsigned slot = atomicAdd(&hoff[mybid[t]], 1u);
        stage[slot] = make_uint2(myrec[t], __float_as_uint(myw[t]));
      }
    }
    __syncthreads();
    uint2* dstp = &recs[(size_t)(b - nCvt) * 768];
    dstp[tid] = stage[tid];
    dstp[tid + 256] = stage[tid + 256];
    dstp[tid + 512] = stage[tid + 512];
  } else if (b < nCvt + nBkt + 512) {
    int bb = b - nCvt - nBkt;
    int mat = bb >> 6, rem = bb & 63;
    int k0 = (rem >> 3) * 32, n0 = (rem & 7) * 32;
    const float* src = (mat < 6) ? (W + (size_t)mat * 65536) : (T + (size_t)(mat - 6) * 65536);
    int r = tid >> 3, c4 = (tid & 7) * 4;
    const float4 v = *(const float4*)&src[(size_t)(k0 + r) * 256 + n0 + c4];
    tile[r][c4 + 0] = v.x; tile[r][c4 + 1] = v.y; tile[r][c4 + 2] = v.z; tile[r][c4 + 3] = v.w;
    __syncthreads();
    float o[4] = {tile[c4 + 0][r], tile[c4 + 1][r], tile[c4 + 2][r], tile[c4 + 3][r]};
    u16 hh[4], ll[4];
#pragma unroll
    for (int q = 0; q < 4; ++q) split2(o[q], hh[q], ll[q]);
    size_t off = (size_t)mat * 65536 + (size_t)(n0 + r) * 256 + k0 + c4;
    *(ushort4*)&Wth[off] = *(ushort4*)hh;
    *(ushort4*)&Wtl[off] = *(ushort4*)ll;
  } else {
    int bn = b - nCvt - nBkt - 512;    // 0..127
    int n0 = bn * 64;
    int w = tid >> 6, lane = tid & 63;
    for (int it = 0; it < 16; ++it) {
      int nl = it * 4 + w;
      int node = n0 + nl;
      const float4 v = *(const float4*)&x[(size_t)node * 256 + lane * 4];
      u16 hh[4], ll[4];
      split2(v.x, hh[0], ll[0]); split2(v.y, hh[1], ll[1]);
      split2(v.z, hh[2], ll[2]); split2(v.w, hh[3], ll[3]);
      *(ushort4*)&Hh[(size_t)node * 256 + lane * 4] = *(ushort4*)hh;
      *(ushort4*)&Hl[(size_t)node * 256 + lane * 4] = *(ushort4*)ll;
      float s = wave_sum(v.x * v.x + v.y * v.y + v.z * v.z + v.w * v.w);
      if (lane == 0) { float nr = sqrtf(s); nrm[node] = nr; inv[nl] = 1.f / nr; }
    }
    __syncthreads();
    float s = 0.f;
    for (int i = 0; i < 64; ++i) s += x[(size_t)(n0 + i) * 256 + tid] * inv[i];
    Spart[bn * 256 + tid] = s;
  }
}

// ==== k_reorder: WAVE per (bucket,chunk); lane i owns segment i; shfl prefix-sum ====
__global__ void k_reorder(const u16* __restrict__ sct, const uint2* __restrict__ recs,
                          uint2* __restrict__ recs2, int* __restrict__ bcnt2, int nBkt) {
  const int wid = blockIdx.x * 4 + (threadIdx.x >> 6);  // 0..6143
  const int lane = threadIdx.x & 63;
  const int bid = wid >> 3;       // bucket 0..767
  const int c = wid & 7;          // chunk 0..7
  const int nseg = nBkt >> 3;     // 64 for E=131072
  unsigned cnt = 0, start = 0;
  int bb = c * nseg + lane;
  if (lane < nseg) {
    unsigned sc = sct[(size_t)bb * 768 + bid];
    start = sc & 2047u; cnt = sc >> 11;
  }
  unsigned pre = cnt;
#pragma unroll
  for (int off = 1; off < 64; off <<= 1) {
    unsigned v = __shfl_up(pre, off, 64);
    if (lane >= off) pre += v;
  }
  unsigned excl = pre - cnt;
  unsigned total = __shfl(pre, 63, 64);
  uint2* dst = &recs2[(size_t)bid * (8 * CCAP) + (size_t)c * CCAP];
  const uint2* rp = &recs[(size_t)bb * 768 + start];
  for (unsigned k = 0; k < cnt; ++k) {
    unsigned o = excl + k;
    if (o < CCAP) dst[o] = rp[k];
  }
  if (lane == 0) bcnt2[bid * 8 + c] = (total > CCAP) ? CCAP : total;
}

// ==== stage A (l0, max heterogeneous pack):
//  mode0 GEMM l0 (768) | M-build l0 (768) | mode2 RAW x.xT (512) | dinv (128) ====
__global__ __launch_bounds__(256, 2) void k_stageA(
    const u16* __restrict__ Hinh, const u16* __restrict__ Hinl,
    const u16* __restrict__ Wth, const u16* __restrict__ Wtl,
    u16* __restrict__ XWTh, u16* __restrict__ XWTl,
    const uint2* __restrict__ recs2, const int* __restrict__ bcnt2,
    u16* __restrict__ Mbh, u16* __restrict__ Mbl,
    float* __restrict__ Abuf,
    const float* __restrict__ x, const float* __restrict__ Spart,
    const float* __restrict__ nrm, float* __restrict__ dinv) {
  extern __shared__ u16 lds[];
  const int b = blockIdx.x;
  if (b < 768) {
    mfma_body<0, false>(lds, Hinh, Hinl, Wth, Wtl,
                        nullptr, XWTh, XWTl, nullptr, nullptr, nullptr,
                        b >> 7, b & 127, 0);
  } else if (b < 1536) {
    mbuild_body((float*)lds, b - 768, 0, recs2, bcnt2, nullptr, Mbh, Mbl);
  } else if (b < 2048) {
    int bb = b - 1536;
    int g = bb & 31, r = bb >> 5;      // r: 0..15 -> bxm 0..3, bym 0..3
    mfma_body<2, true>(lds, Hinh, Hinl, Hinh, Hinl, Abuf, nullptr, nullptr,
                       nullptr, nullptr, nullptr, r >> 2, r & 3, g);
  } else {
    float* Sl = (float*)lds;
    const int tid = threadIdx.x;
    float s = 0.f;
    for (int bb = 0; bb < 128; ++bb) s += Spart[bb * 256 + tid];
    Sl[tid] = s;
    __syncthreads();
    int base = (b - 2048) * 64;
    int w = tid >> 6, lane = tid & 63;
    const float4 sv = *(const float4*)&Sl[lane * 4];
    for (int it = 0; it < 16; ++it) {
      int node = base + it * 4 + w;
      const float4 v = *(const float4*)&x[(size_t)node * 256 + lane * 4];
      float s2 = wave_sum(v.x * sv.x + v.y * sv.y + v.z * sv.z + v.w * sv.w);
      if (lane == 0) {
        float rowsum = s2 / nrm[node];
        dinv[node] = rsqrtf(fabsf(rowsum) + ZEROF);
      }
    }
  }
}

// ==== stage A2 (l1, fused heterogeneous pack): mode0 GEMM l1 (768) | M-build l1 (768) ====
__global__ __launch_bounds__(256, 2) void k_stageA2(
    const u16* __restrict__ H2h, const u16* __restrict__ H2l,
    const u16* __restrict__ Wth, const u16* __restrict__ Wtl,
    u16* __restrict__ XWTh, u16* __restrict__ XWTl,
    const uint2* __restrict__ recs2, const int* __restrict__ bcnt2,
    const float* __restrict__ Abuf,
    u16* __restrict__ Mbh, u16* __restrict__ Mbl) {
  extern __shared__ u16 lds[];
  const int b = blockIdx.x;
  if (b < 768) {
    mfma_body<0, false>(lds, H2h, H2l, Wth + (size_t)768 * 256, Wtl + (size_t)768 * 256,
                        nullptr, XWTh, XWTl, nullptr, nullptr, nullptr,
                        b >> 7, b & 127, 0);
  } else {
    mbuild_body((float*)lds, b - 768, 1, recs2, bcnt2, Abuf, Mbh, Mbl);
  }
}

// ==== stage B: mode1 only (HALF 64x64, 512 blocks) ====
__global__ __launch_bounds__(256, 2) void k_stageB(
    const u16* __restrict__ XWTh, const u16* __restrict__ XWTl,
    const u16* __restrict__ Mbh, const u16* __restrict__ Mbl,
    u16* __restrict__ Houth, u16* __restrict__ Houtl, const float* __restrict__ bias) {
  extern __shared__ u16 lds[];
  const int b = blockIdx.x;
  int g = b & 31, r = b >> 5;          // r: 0..15 -> bxm 0..3, bym 0..3
  mfma_body<1, true>(lds, XWTh, XWTl, Mbh, Mbl,
                     nullptr, Houth, Houtl, nullptr, nullptr, bias,
                     r >> 2, r & 3, g);
}

// ============ stage C: mode4 (half, 512): tmp = H @ T ============
__global__ __launch_bounds__(256, 2) void k_stageC(
    const u16* __restrict__ Wth, const u16* __restrict__ Wtl, int l,
    const u16* __restrict__ Hh, const u16* __restrict__ Hl,
    u16* __restrict__ tmph, u16* __restrict__ tmpl) {
  extern __shared__ u16 lds[];
  const int b = blockIdx.x;
  mfma_body<4, true>(lds, Wth + (size_t)(6 + l) * 65536, Wtl + (size_t)(6 + l) * 65536,
                     Hh, Hl, nullptr, tmph, tmpl, nullptr, nullptr, nullptr,
                     b & 127, b >> 7, 0);
}

// ============ stage D: A update. scaled!=0 (l0): MODE 5 applies the deferred scale ============
__global__ __launch_bounds__(256, 2) void k_stageD(
    const u16* __restrict__ tmph, const u16* __restrict__ tmpl,
    const u16* __restrict__ Hh, const u16* __restrict__ Hl,
    float* __restrict__ Abuf,
    const float* __restrict__ nrm, const float* __restrict__ dinv, int scaled) {
  extern __shared__ u16 lds[];
  const int b = blockIdx.x;
  int g = b & 31, r = b >> 5;
  if (scaled)
    mfma_body<5, true>(lds, tmph, tmpl, Hh, Hl, Abuf, nullptr, nullptr,
                       nrm, dinv, nullptr, r >> 2, r & 3, g);
  else
    mfma_body<3, true>(lds, tmph, tmpl, Hh, Hl, Abuf, nullptr, nullptr,
                       nullptr, nullptr, nullptr, r >> 2, r & 3, g);
}

// ============ fused maps ============
__global__ void k_maps(const float* __restrict__ Abuf, const float* __restrict__ emf,
                       const float* __restrict__ pmf, float* __restrict__ out) {
  __shared__ float sme[256], smp[256], red[256];
  const int g = blockIdx.x, tid = threadIdx.x, w = tid >> 6, lane = tid & 63;
  const int j0 = g * 256 + lane * 4;
  const float4 pmv = *(const float4*)&pmf[j0];
  const float4 emv = *(const float4*)&emf[j0];
  for (int it = 0; it < 64; ++it) {
    int nl = it * 4 + w;
    const float4 a = *(const float4*)&Abuf[((size_t)g * 256 + nl) * 256 + lane * 4];
    float me = a.x * pmv.x + a.y * pmv.y + a.z * pmv.z + a.w * pmv.w;
    float mp = a.x * emv.x + a.y * emv.y + a.z * emv.z + a.w * emv.w;
#pragma unroll
    for (int off = 32; off > 0; off >>= 1) {
      me += __shfl_down(me, off, 64);
      mp += __shfl_down(mp, off, 64);
    }
    if (lane == 0) { sme[nl] = me; smp[nl] = mp; }
  }
  __syncthreads();
  for (int which = 0; which < 2; ++which) {
    float v = which ? smp[tid] : sme[tid];
    red[tid] = v; __syncthreads();
    for (int s = 128; s > 0; s >>= 1) { if (tid < s) red[tid] = fminf(red[tid], red[tid + s]); __syncthreads(); }
    float mn = red[0]; __syncthreads();
    red[tid] = v; __syncthreads();
    for (int s = 128; s > 0; s >>= 1) { if (tid < s) red[tid] = fmaxf(red[tid], red[tid + s]); __syncthreads(); }
    float mx = red[0]; __syncthreads();
    float m = (v - mn) / (mx - mn + ZEROF);
    red[tid] = m; __syncthreads();
    for (int s = 128; s > 0; s >>= 1) { if (tid < s) red[tid] += red[tid + s]; __syncthreads(); }
    float sum = red[0]; __syncthreads();
    out[which * NND + g * 256 + tid] = m / (sum + ZEROF);
  }
}

// ================= launch =================
extern "C" void kernel_launch(void* const* d_in, const int* in_sizes, int n_in,
                              void* d_out, int out_size, void* d_ws, size_t ws_size,
                              hipStream_t stream) {
  const float* x = (const float*)d_in[0];
  const unsigned char* em_raw = (const unsigned char*)d_in[7];
  const unsigned char* pm_raw = (const unsigned char*)d_in[8];
  const float* W  = (const float*)d_in[9];
  const float* bg = (const float*)d_in[10];
  const float* T  = (const float*)d_in[11];
  float* out = (float*)d_out;
  const int E_ = in_sizes[2];

  const int nCvt = (2 * NND) / 256;          // 64
  const int nBkt = (E_ + 255) / 256;         // 512 for E=131072

  float* ws = (float*)d_ws;
  size_t o = 0;
  float* Abuf = ws + o; o += (size_t)NND * 256;
  u16* Mbh_l0 = (u16*)(ws + o); o += (size_t)NGRP * 3 * 65536 / 2;
  u16* Mbl_l0 = (u16*)(ws + o); o += (size_t)NGRP * 3 * 65536 / 2;
  u16* Mbh_l1 = (u16*)(ws + o); o += (size_t)NGRP * 3 * 65536 / 2;
  u16* Mbl_l1 = (u16*)(ws + o); o += (size_t)NGRP * 3 * 65536 / 2;
  u16* Hh   = (u16*)(ws + o); o += (size_t)NND * 256 / 2;
  u16* Hl   = (u16*)(ws + o); o += (size_t)NND * 256 / 2;
  u16* H2h  = (u16*)(ws + o); o += (size_t)NND * 256 / 2;
  u16* H2l  = (u16*)(ws + o); o += (size_t)NND * 256 / 2;
  u16* tmph = (u16*)(ws + o); o += (size_t)NND * 256 / 2;
  u16* tmpl = (u16*)(ws + o); o += (size_t)NND * 256 / 2;
  u16* XWTh = (u16*)(ws + o); o += (size_t)768 * NND / 2;
  u16* XWTl = (u16*)(ws + o); o += (size_t)768 * NND / 2;
  u16* Wth  = (u16*)(ws + o); o += (size_t)8 * 65536 / 2;
  u16* Wtl  = (u16*)(ws + o); o += (size_t)8 * 65536 / 2;
  float* nrm   = ws + o; o += NND;
  float* dinv  = ws + o; o += NND;
  float* Spart = ws + o; o += 128 * 256;
  float* emf   = ws + o; o += NND;
  float* pmf   = ws + o; o += NND;
  u16* sct     = (u16*)(ws + o); o += (size_t)nBkt * 768 / 2;
  uint2* recs  = (uint2*)(ws + o); o += (size_t)nBkt * 768 * 2;
  uint2* recs2 = (uint2*)(ws + o); o += (size_t)768 * 8 * CCAP * 2;
  int* bcnt2   = (int*)(ws + o); o += (size_t)768 * 8;

  const float* ew0 = (const float*)d_in[2];
  const float* ew1 = (const float*)d_in[4];
  const float* ew2 = (const float*)d_in[6];

  k_prep<<<nCvt + nBkt + 512 + 128, 256, 0, stream>>>(
      (const int*)d_in[1], (const int*)d_in[3], (const int*)d_in[5], em_raw, pm_raw,
      W, T, x, ew0, ew1, ew2, emf, pmf, Wth, Wtl, sct, recs,
      nrm, Spart, Hh, Hl, E_, nCvt, nBkt);

  k_reorder<<<1536, 256, 0, stream>>>(sct, recs, recs2, bcnt2, nBkt);

  // ---- layer 0 ----
  k_stageA<<<2176, 256, SM_FULL, stream>>>(Hh, Hl, Wth, Wtl, XWTh, XWTl,
                                           recs2, bcnt2, Mbh_l0, Mbl_l0, Abuf,
                                           x, Spart, nrm, dinv);
  k_stageB<<<512, 256, SM_HALF, stream>>>(XWTh, XWTl, Mbh_l0, Mbl_l0, H2h, H2l, bg);
  k_stageC<<<512, 256, SM_HALF, stream>>>(Wth, Wtl, 0, H2h, H2l, tmph, tmpl);
  k_stageD<<<512, 256, SM_HALF, stream>>>(tmph, tmpl, H2h, H2l, Abuf, nrm, dinv, 1);

  // ---- layer 1 ----
  k_stageA2<<<1536, 256, SM_FULL, stream>>>(H2h, H2l, Wth, Wtl, XWTh, XWTl,
                                            recs2, bcnt2, Abuf, Mbh_l1, Mbl_l1);
  k_stageB<<<512, 256, SM_HALF, stream>>>(XWTh, XWTl, Mbh_l1, Mbl_l1, Hh, Hl, bg + 768);
  k_stageC<<<512, 256, SM_HALF, stream>>>(Wth, Wtl, 1, Hh, Hl, tmph, tmpl);
  k_stageD<<<512, 256, SM_HALF, stream>>>(tmph, tmpl, Hh, Hl, Abuf, nullptr, nullptr, 0);

  k_maps<<<NGRP, 256, 0, stream>>>(Abuf, emf, pmf, out);
}

// Round 15
// 252.401 us; speedup vs baseline: 1.1216x; 1.0053x over previous
//
#include <hip/hip_runtime.h>

#define NND   8192
#define DDIM  256
#define NGRP  32
#define ZEROF 1e-8f
#define TSTR  72   // epilogue transpose tile stride in u16
#define CCAP 192   // reorder per-(bucket,seg-chunk) capacity (mean 64, +16 sigma)
// Round-15: HALF modes use 3 buffers -> ONE barrier per K-step (write target
// (N+1)%3 vs in-flight reads (N-1)%3, distinct mod 3; landed-barrier gives
// cross-wave visibility). FULL stays 2-buffer/2-barrier (3x24KB > 64KB dyn-LDS).
// + s_setprio(1) around MFMA cluster (T5: pays in hetero-packed dispatches where
// GEMM waves co-reside with mbuild gather waves).
#define SM_HALF 49152
#define SM_FULL 49152

typedef unsigned short u16;
typedef __attribute__((ext_vector_type(8))) short short8v;
typedef __attribute__((ext_vector_type(4))) float float4v;

__device__ __forceinline__ void gl16(const u16* g, u16* l) {
  __builtin_amdgcn_global_load_lds(
      (const __attribute__((address_space(1))) unsigned int*)g,
      (__attribute__((address_space(3))) unsigned int*)l, 16, 0, 0);
}

template<int N>
__device__ __forceinline__ void waitv() {
  if constexpr (N == 0)      asm volatile("s_waitcnt vmcnt(0)" ::: "memory");
  else if constexpr (N == 4) asm volatile("s_waitcnt vmcnt(4)" ::: "memory");
  else                       asm volatile("s_waitcnt vmcnt(6)" ::: "memory");
}

__device__ inline u16 f2bf(float x) {
  unsigned u = __float_as_uint(x);
  u += 0x7fffu + ((u >> 16) & 1u);
  return (u16)(u >> 16);
}
__device__ inline float bf2f(u16 h) { return __uint_as_float((unsigned)h << 16); }
__device__ inline void split2(float x, u16& h, u16& l) {
  h = f2bf(x);
  l = f2bf(x - bf2f(h));
}

__device__ inline float wave_sum(float v) {
#pragma unroll
  for (int off = 32; off > 0; off >>= 1) v += __shfl_down(v, off, 64);
  return v;
}

// ================= unified split-bf16 MFMA GEMM body (async nbuf, counted vmcnt) =================
// C-tile 64 x (HALF?64:128), 4 waves, 16x16x32 bf16 MFMA, split-bf16x3.
// MODE 0: XWT[c][node] = (H @ Wcat)^T       a=H(node), b=Wt(c)          [full]
// MODE 1: Hout = relu(b3 + M @ XWcat)       a=XWT(d), b=Mb h/l, K=768   [half]
// MODE 2: A_raw = x.xT (UNSCALED)           a=b=x                       [half]
// MODE 3: A = 0.5A + 0.5 sigmoid(t.HT)      a=tmp, b=H                  [half]
// MODE 5: A = 0.5*A_raw*scale + 0.5 sig(.)  a=tmp, b=H; scale=di*dj/(ni*nj+e) [half]
// MODE 4: tmp[node][d] = H @ T              a=Tt(d), b=H(node)          [half]
template<int MODE, bool HALF>
__device__ __forceinline__ void mfma_body(
    u16* lds,
    const u16* __restrict__ Ah_g, const u16* __restrict__ Al_g,
    const u16* __restrict__ Bh_g, const u16* __restrict__ Bl_g,
    float* __restrict__ Cf, u16* __restrict__ Ch, u16* __restrict__ Cl,
    const float* __restrict__ nrm, const float* __restrict__ dinv,
    const float* __restrict__ bias,
    int bxm, int bym, int g) {
  const int BS    = HALF ? 8192 : 12288;   // u16 per buffer
  const int NBUF  = HALF ? 3 : 2;
  const int BOFF  = 4096;                  // Bh start within buffer
  const int BLOFF = 4096 + (HALF ? 2048 : 4096);
  const int NJ = HALF ? 2 : 4;
  const int NLD = HALF ? 4 : 6;            // gl16 per STAGE
  const int tid = threadIdx.x;
  const int col0 = bxm * (HALF ? 64 : 128);
  const int w = tid >> 6, lane = tid & 63;
  const int lm = lane & 15, lq = lane >> 4;
  const int wr = (w >> 1) * 32, wc = (w & 1) * (HALF ? 32 : 64);
  const int TOTAL = (MODE == 1) ? 24 : 8;

  const int m_ = tid >> 2;
  const int sw = ((tid & 3) ^ (m_ & 3)) * 8;   // pre-swizzled k-slot (u16)
  const int wbase = (tid >> 6) * 512;          // wave-uniform lds offset (u16)

  float4v acc[2][4];
#pragma unroll
  for (int i = 0; i < 2; ++i)
#pragma unroll
    for (int j = 0; j < NJ; ++j) acc[i][j] = (float4v)0.f;

  auto STAGE = [&](int buf, int tt, int kk) {
    u16* base = lds + buf * BS;
    size_t aoff;
    if (MODE == 1)
      aoff = (size_t)(tt * 256 + bym * 64 + m_) * 8192 + (size_t)(g * 256 + kk + sw);
    else if (MODE == 2 || MODE == 3 || MODE == 5)
      aoff = (size_t)(g * 256 + bym * 64 + m_) * 256 + kk + sw;
    else
      aoff = (size_t)(bym * 64 + m_) * 256 + kk + sw;
    gl16(&Ah_g[aoff], base + wbase);
    gl16(&Al_g[aoff], base + 2048 + wbase);
    size_t bbase = (MODE == 1) ? ((size_t)(g * 3 + tt) << 16)
                 : ((MODE == 2 || MODE == 3 || MODE == 5) ? ((size_t)g << 16) : (size_t)0);
    size_t boff = bbase + (size_t)(col0 + m_) * 256 + kk + sw;
    gl16(&Bh_g[boff], base + BOFF + wbase);
    gl16(&Bl_g[boff], base + BLOFF + wbase);
    if (!HALF) {
      size_t boff2 = boff + (size_t)64 * 256;   // rows 64..127 ((64+m)&3 == m&3 -> same sw)
      gl16(&Bh_g[boff2], base + BOFF + 2048 + wbase);
      gl16(&Bl_g[boff2], base + BLOFF + 2048 + wbase);
    }
  };

  STAGE(0, 0, 0);
  waitv<0>();
  __builtin_amdgcn_s_barrier();
  __builtin_amdgcn_sched_barrier(0);
  int cur = 0;
  for (int step = 0; step < TOTAL; ++step) {
    int nxt = step + 1;
    if (nxt < TOTAL) {
      int tt = (MODE == 1) ? (nxt >> 3) : 0;
      int kk = (MODE == 1) ? ((nxt & 7) * 32) : (nxt * 32);
      int nb = HALF ? (nxt % 3) : (cur ^ 1);
      STAGE(nb, tt, kk);           // in flight across barrier(s) below
      waitv<NLD>();                // own STAGE(step) landed; prefetch stays outstanding
    } else {
      waitv<0>();                  // final step: drain everything
    }
    __builtin_amdgcn_s_barrier();  // all waves' buf-cur data landed
    __builtin_amdgcn_sched_barrier(0);
    u16* base = lds + cur * BS;
    short8v ah[2], al[2], bh[4], bl[4];
#pragma unroll
    for (int i = 0; i < 2; ++i) {
      int r = wr + i * 16 + lm;
      int sa = (lq ^ (r & 3)) * 8;
      ah[i] = *(const short8v*)&base[r * 32 + sa];
      al[i] = *(const short8v*)&base[2048 + r * 32 + sa];
    }
#pragma unroll
    for (int j = 0; j < NJ; ++j) {
      int rb = wc + j * 16 + lm;
      int sb = (lq ^ (rb & 3)) * 8;
      bh[j] = *(const short8v*)&base[BOFF + rb * 32 + sb];
      bl[j] = *(const short8v*)&base[BLOFF + rb * 32 + sb];
    }
    __builtin_amdgcn_s_setprio(1);
#pragma unroll
    for (int i = 0; i < 2; ++i)
#pragma unroll
      for (int j = 0; j < NJ; ++j) {
        acc[i][j] = __builtin_amdgcn_mfma_f32_16x16x32_bf16(ah[i], bh[j], acc[i][j], 0, 0, 0);
        acc[i][j] = __builtin_amdgcn_mfma_f32_16x16x32_bf16(ah[i], bl[j], acc[i][j], 0, 0, 0);
        acc[i][j] = __builtin_amdgcn_mfma_f32_16x16x32_bf16(al[i], bh[j], acc[i][j], 0, 0, 0);
      }
    __builtin_amdgcn_s_setprio(0);
    if (!HALF) {
      __builtin_amdgcn_s_barrier();  // 2-buffer: readers done -> next STAGE may overwrite
    }
    cur = HALF ? (nxt % 3) : (cur ^ 1);
  }

  // ---- epilogues (frag: col=lm, row=lq*4+r). Tt aliases lds (all buffers drained;
  //      MODE 0/1 epilogue begins with __syncthreads before LDS reuse) ----
  u16* Tt = lds;
  if (MODE == 2 || MODE == 3 || MODE == 5) {
#pragma unroll
    for (int i = 0; i < 2; ++i) {
#pragma unroll
      for (int r = 0; r < 4; ++r) {
        int grow = g * 256 + bym * 64 + wr + i * 16 + lq * 4 + r;
        float di = 0.f, ni = 0.f;
        if (MODE == 5) { di = dinv[grow]; ni = nrm[grow]; }
#pragma unroll
        for (int j = 0; j < NJ; ++j) {
          int gcol = col0 + wc + j * 16 + lm;
          size_t ci = (size_t)grow * 256 + gcol;
          float v = acc[i][j][r];
          if (MODE == 2) {
            Cf[ci] = v;                      // RAW dot; scale deferred to MODE 5 (D-l0)
          } else if (MODE == 3) {
            Cf[ci] = 0.5f * Cf[ci] + 0.5f * (1.f / (1.f + expf(-v)));
          } else {
            int gj = g * 256 + gcol;
            float scale = di * dinv[gj] / (ni * nrm[gj] + ZEROF);
            Cf[ci] = 0.5f * Cf[ci] * scale + 0.5f * (1.f / (1.f + expf(-v)));
          }
        }
      }
    }
  } else {
    float bsum[8];
    if (MODE == 1) {
#pragma unroll
      for (int i = 0; i < 2; ++i)
#pragma unroll
        for (int r = 0; r < 4; ++r) {
          int d = bym * 64 + wr + i * 16 + lq * 4 + r;
          bsum[i * 4 + r] = bias[d] + bias[256 + d] + bias[512 + d];
        }
    }
    u16 hv[32], lv[32];
#pragma unroll
    for (int i = 0; i < 2; ++i)
#pragma unroll
      for (int j = 0; j < NJ; ++j)
#pragma unroll
        for (int r = 0; r < 4; ++r) {
          float v = acc[i][j][r];
          if (MODE == 1) v = fmaxf(v + bsum[i * 4 + r], 0.f);
          split2(v, hv[(i * 4 + r) * NJ + j], lv[(i * 4 + r) * NJ + j]);
        }
    int ebase1 = (MODE == 1) ? (g * 256 + col0) : col0;
    int ebase2 = bym * 64;
    size_t estride = (MODE == 0) ? 8192 : 256;
#pragma unroll
    for (int ph = 0; ph < 2; ++ph) {
      __syncthreads();
      const u16* sv = ph ? lv : hv;
#pragma unroll
      for (int i = 0; i < 2; ++i)
#pragma unroll
        for (int j = 0; j < NJ; ++j)
#pragma unroll
          for (int r = 0; r < 4; ++r)
            Tt[(wc + j * 16 + lm) * TSTR + wr + i * 16 + lq * 4 + r] = sv[(i * 4 + r) * NJ + j];
      __syncthreads();
      u16* dst = ph ? Cl : Ch;
      int cc0 = tid >> 3, mm0 = (tid & 7) * 8;
#pragma unroll
      for (int it = 0; it < (HALF ? 2 : 4); ++it) {
        int cc = it * 32 + cc0;
        short8v v = *(const short8v*)&Tt[cc * TSTR + mm0];
        *(short8v*)&dst[(size_t)(ebase1 + cc) * estride + ebase2 + mm0] = v;
      }
    }
  }
}

// ---- M-build block body: dense 32x256 fp32 tile from BUCKET-MAJOR records ----
__device__ __forceinline__ void mbuild_body(
    float* tile, int bid, int l,
    const uint2* __restrict__ recs2, const int* __restrict__ bcnt2,
    const float* __restrict__ Abuf, u16* __restrict__ Mbh, u16* __restrict__ Mbl) {
  const int tid = threadIdx.x;
  int gt = bid >> 3, chunk = bid & 7;
  int g = gt / 3;
  float4 z = make_float4(0.f, 0.f, 0.f, 0.f);
#pragma unroll
  for (int k = 0; k < 8; ++k) ((float4*)tile)[k * 256 + tid] = z;
  __syncthreads();
#pragma unroll
  for (int c = 0; c < 8; ++c) {
    int cnt = bcnt2[bid * 8 + c];
    const uint2* rp = &recs2[(size_t)bid * (8 * CCAP) + (size_t)c * CCAP];
    for (int k = tid; k < cnt; k += 256) {
      uint2 r = rp[k];
      int s = r.x & 255, d5 = (r.x >> 8) & 31;
      float w = l ? Abuf[(size_t)(g * 256 + s) * 256 + chunk * 32 + d5]
                  : __uint_as_float(r.y);
      atomicAdd(&tile[d5 * 256 + s], w);
    }
  }
  __syncthreads();
  size_t base4 = ((size_t)gt << 14) + ((size_t)chunk << 11);  // ushort4 units
#pragma unroll
  for (int k = 0; k < 8; ++k) {
    float4 f = ((float4*)tile)[k * 256 + tid];
    ushort4 h, lo;
    split2(f.x, h.x, lo.x); split2(f.y, h.y, lo.y);
    split2(f.z, h.z, lo.z); split2(f.w, h.w, lo.w);
    ((ushort4*)Mbh)[base4 + k * 256 + tid] = h;
    ((ushort4*)Mbl)[base4 + k * 256 + tid] = lo;
  }
}

// ===== prep: mask cvt | edge bucketing (atomic-free) | transpose/split W | norms+x-split =====
__global__ void k_prep(const int* __restrict__ e0, const int* __restrict__ e1,
                       const int* __restrict__ e2, const unsigned char* __restrict__ m0,
                       const unsigned char* __restrict__ m1,
                       const float* __restrict__ W, const float* __restrict__ T,
                       const float* __restrict__ x,
                       const float* __restrict__ ew0, const float* __restrict__ ew1,
                       const float* __restrict__ ew2,
                       float* __restrict__ emf, float* __restrict__ pmf,
                       u16* __restrict__ Wth, u16* __restrict__ Wtl,
                       u16* __restrict__ sct, uint2* __restrict__ recs,
                       float* __restrict__ nrm, float* __restrict__ Spart,
                       u16* __restrict__ Hh, u16* __restrict__ Hl,
                       int E_, int nCvt, int nBkt) {
  __shared__ float tile[32][33];
  __shared__ float inv[64];
  __shared__ int nz[1];
  __shared__ unsigned int hcnt[768];
  __shared__ unsigned int hoff[768];
  __shared__ unsigned int ppart[256];
  __shared__ uint2 stage[768];
  const int b = blockIdx.x, tid = threadIdx.x;
  if (b < nCvt) {
    // ---- mask dtype detect + convert (2*NND values) ----
    if (tid == 0) nz[0] = 0;
    __syncthreads();
    int i4 = tid * 4;
    int c = (m0[i4 + 1] != 0) + (m0[i4 + 2] != 0) + (m0[i4 + 3] != 0);
    if (c) atomicAdd(&nz[0], c);
    __syncthreads();
    int fM = (nz[0] == 0);
    int i = b * 256 + tid;
    if (i < NND) {
      unsigned char v = fM ? m0[4 * i] : m0[i];
      emf[i] = 1.f - (float)(v != 0);
    } else {
      int j = i - NND;
      unsigned char v = fM ? m1[4 * j] : m1[j];
      pmf[j] = 1.f - (float)(v != 0);
    }
  } else if (b < nCvt + nBkt) {
    // ---- atomic-free edge bucketing: block-private segments, LDS hist+scan ----
    if (tid == 0) nz[0] = 0;
    hcnt[tid] = 0; hcnt[tid + 256] = 0; hcnt[tid + 512] = 0;
    __syncthreads();
    if (e0[2 * tid + 1] != 0) atomicAdd(&nz[0], 1);
    __syncthreads();
    int fE = (nz[0] == 0);   // int64-format edges
    int e = (b - nCvt) * 256 + tid;
    bool valid = (e < E_);
    int mybid[3]; unsigned int myrec[3]; float myw[3];
    if (valid) {
#pragma unroll
      for (int t = 0; t < 3; ++t) {
        const int* ei = (t == 0) ? e0 : ((t == 1) ? e1 : e2);
        int src = fE ? ei[2 * e] : ei[e];
        int dst = fE ? ei[2 * (E_ + e)] : ei[E_ + e];
        int g = src >> 8, s = src & 255, d = dst & 255;
        mybid[t] = ((g * 3 + t) << 3) | (d >> 5);
        myrec[t] = (unsigned)(((d & 31) << 8) | s);
        myw[t] = (t == 0 ? ew0 : (t == 1 ? ew1 : ew2))[e];
        atomicAdd(&hcnt[mybid[t]], 1u);
      }
    }
    __syncthreads();
    unsigned c0 = hcnt[3 * tid], c1 = hcnt[3 * tid + 1], c2 = hcnt[3 * tid + 2];
    unsigned tsum = c0 + c1 + c2;
    ppart[tid] = tsum;
    __syncthreads();
    for (int off = 1; off < 256; off <<= 1) {
      unsigned v = (tid >= off) ? ppart[tid - off] : 0u;
      __syncthreads();
      ppart[tid] += v;
      __syncthreads();
    }
    unsigned base = ppart[tid] - tsum;   // exclusive prefix
    hoff[3 * tid] = base;
    hoff[3 * tid + 1] = base + c0;
    hoff[3 * tid + 2] = base + c0 + c1;
    __syncthreads();
#pragma unroll
    for (int k = 0; k < 3; ++k) {
      int bin = tid + k * 256;
      unsigned cc = hcnt[bin]; if (cc > 31u) cc = 31u;
      sct[(size_t)(b - nCvt) * 768 + bin] = (u16)(hoff[bin] | (cc << 11));
    }
    __syncthreads();
    if (valid) {
#pragma unroll
      for (int t = 0; t < 3; ++t) {
        unsigned slot = atomicAdd(&hoff[mybid[t]], 1u);
        stage[slot] = make_uint2(myrec[t], __float_as_uint(myw[t]));
      }
    }
    __syncthreads();
    uint2* dstp = &recs[(size_t)(b - nCvt) * 768];
    dstp[tid] = stage[tid];
    dstp[tid + 256] = stage[tid + 256];
    dstp[tid + 512] = stage[tid + 512];
  } else if (b < nCvt + nBkt + 512) {
    int bb = b - nCvt - nBkt;
    int mat = bb >> 6, rem = bb & 63;
    int k0 = (rem >> 3) * 32, n0 = (rem & 7) * 32;
    const float* src = (mat < 6) ? (W + (size_t)mat * 65536) : (T + (size_t)(mat - 6) * 65536);
    int r = tid >> 3, c4 = (tid & 7) * 4;
    const float4 v = *(const float4*)&src[(size_t)(k0 + r) * 256 + n0 + c4];
    tile[r][c4 + 0] = v.x; tile[r][c4 + 1] = v.y; tile[r][c4 + 2] = v.z; tile[r][c4 + 3] = v.w;
    __syncthreads();
    float o[4] = {tile[c4 + 0][r], tile[c4 + 1][r], tile[c4 + 2][r], tile[c4 + 3][r]};
    u16 hh[4], ll[4];
#pragma unroll
    for (int q = 0; q < 4; ++q) split2(o[q], hh[q], ll[q]);
    size_t off = (size_t)mat * 65536 + (size_t)(n0 + r) * 256 + k0 + c4;
    *(ushort4*)&Wth[off] = *(ushort4*)hh;
    *(ushort4*)&Wtl[off] = *(ushort4*)ll;
  } else {
    int bn = b - nCvt - nBkt - 512;    // 0..127
    int n0 = bn * 64;
    int w = tid >> 6, lane = tid & 63;
    for (int it = 0; it < 16; ++it) {
      int nl = it * 4 + w;
      int node = n0 + nl;
      const float4 v = *(const float4*)&x[(size_t)node * 256 + lane * 4];
      u16 hh[4], ll[4];
      split2(v.x, hh[0], ll[0]); split2(v.y, hh[1], ll[1]);
      split2(v.z, hh[2], ll[2]); split2(v.w, hh[3], ll[3]);
      *(ushort4*)&Hh[(size_t)node * 256 + lane * 4] = *(ushort4*)hh;
      *(ushort4*)&Hl[(size_t)node * 256 + lane * 4] = *(ushort4*)ll;
      float s = wave_sum(v.x * v.x + v.y * v.y + v.z * v.z + v.w * v.w);
      if (lane == 0) { float nr = sqrtf(s); nrm[node] = nr; inv[nl] = 1.f / nr; }
    }
    __syncthreads();
    float s = 0.f;
    for (int i = 0; i < 64; ++i) s += x[(size_t)(n0 + i) * 256 + tid] * inv[i];
    Spart[bn * 256 + tid] = s;
  }
}

// ==== k_reorder: WAVE per (bucket,chunk); lane i owns segment i; shfl prefix-sum ====
__global__ void k_reorder(const u16* __restrict__ sct, const uint2* __restrict__ recs,
                          uint2* __restrict__ recs2, int* __restrict__ bcnt2, int nBkt) {
  const int wid = blockIdx.x * 4 + (threadIdx.x >> 6);  // 0..6143
  const int lane = threadIdx.x & 63;
  const int bid = wid >> 3;       // bucket 0..767
  const int c = wid & 7;          // chunk 0..7
  const int nseg = nBkt >> 3;     // 64 for E=131072
  unsigned cnt = 0, start = 0;
  int bb = c * nseg + lane;
  if (lane < nseg) {
    unsigned sc = sct[(size_t)bb * 768 + bid];
    start = sc & 2047u; cnt = sc >> 11;
  }
  unsigned pre = cnt;
#pragma unroll
  for (int off = 1; off < 64; off <<= 1) {
    unsigned v = __shfl_up(pre, off, 64);
    if (lane >= off) pre += v;
  }
  unsigned excl = pre - cnt;
  unsigned total = __shfl(pre, 63, 64);
  uint2* dst = &recs2[(size_t)bid * (8 * CCAP) + (size_t)c * CCAP];
  const uint2* rp = &recs[(size_t)bb * 768 + start];
  for (unsigned k = 0; k < cnt; ++k) {
    unsigned o = excl + k;
    if (o < CCAP) dst[o] = rp[k];
  }
  if (lane == 0) bcnt2[bid * 8 + c] = (total > CCAP) ? CCAP : total;
}

// ==== stage A (l0, max heterogeneous pack):
//  mode0 GEMM l0 (768) | M-build l0 (768) | mode2 RAW x.xT (512) | dinv (128) ====
__global__ __launch_bounds__(256, 2) void k_stageA(
    const u16* __restrict__ Hinh, const u16* __restrict__ Hinl,
    const u16* __restrict__ Wth, const u16* __restrict__ Wtl,
    u16* __restrict__ XWTh, u16* __restrict__ XWTl,
    const uint2* __restrict__ recs2, const int* __restrict__ bcnt2,
    u16* __restrict__ Mbh, u16* __restrict__ Mbl,
    float* __restrict__ Abuf,
    const float* __restrict__ x, const float* __restrict__ Spart,
    const float* __restrict__ nrm, float* __restrict__ dinv) {
  extern __shared__ u16 lds[];
  const int b = blockIdx.x;
  if (b < 768) {
    mfma_body<0, false>(lds, Hinh, Hinl, Wth, Wtl,
                        nullptr, XWTh, XWTl, nullptr, nullptr, nullptr,
                        b >> 7, b & 127, 0);
  } else if (b < 1536) {
    mbuild_body((float*)lds, b - 768, 0, recs2, bcnt2, nullptr, Mbh, Mbl);
  } else if (b < 2048) {
    int bb = b - 1536;
    int g = bb & 31, r = bb >> 5;      // r: 0..15 -> bxm 0..3, bym 0..3
    mfma_body<2, true>(lds, Hinh, Hinl, Hinh, Hinl, Abuf, nullptr, nullptr,
                       nullptr, nullptr, nullptr, r >> 2, r & 3, g);
  } else {
    float* Sl = (float*)lds;
    const int tid = threadIdx.x;
    float s = 0.f;
    for (int bb = 0; bb < 128; ++bb) s += Spart[bb * 256 + tid];
    Sl[tid] = s;
    __syncthreads();
    int base = (b - 2048) * 64;
    int w = tid >> 6, lane = tid & 63;
    const float4 sv = *(const float4*)&Sl[lane * 4];
    for (int it = 0; it < 16; ++it) {
      int node = base + it * 4 + w;
      const float4 v = *(const float4*)&x[(size_t)node * 256 + lane * 4];
      float s2 = wave_sum(v.x * sv.x + v.y * sv.y + v.z * sv.z + v.w * sv.w);
      if (lane == 0) {
        float rowsum = s2 / nrm[node];
        dinv[node] = rsqrtf(fabsf(rowsum) + ZEROF);
      }
    }
  }
}

// ==== stage A2 (l1, fused heterogeneous pack): mode0 GEMM l1 (768) | M-build l1 (768) ====
__global__ __launch_bounds__(256, 2) void k_stageA2(
    const u16* __restrict__ H2h, const u16* __restrict__ H2l,
    const u16* __restrict__ Wth, const u16* __restrict__ Wtl,
    u16* __restrict__ XWTh, u16* __restrict__ XWTl,
    const uint2* __restrict__ recs2, const int* __restrict__ bcnt2,
    const float* __restrict__ Abuf,
    u16* __restrict__ Mbh, u16* __restrict__ Mbl) {
  extern __shared__ u16 lds[];
  const int b = blockIdx.x;
  if (b < 768) {
    mfma_body<0, false>(lds, H2h, H2l, Wth + (size_t)768 * 256, Wtl + (size_t)768 * 256,
                        nullptr, XWTh, XWTl, nullptr, nullptr, nullptr,
                        b >> 7, b & 127, 0);
  } else {
    mbuild_body((float*)lds, b - 768, 1, recs2, bcnt2, Abuf, Mbh, Mbl);
  }
}

// ==== stage B: mode1 only (HALF 64x64, 512 blocks) ====
__global__ __launch_bounds__(256, 2) void k_stageB(
    const u16* __restrict__ XWTh, const u16* __restrict__ XWTl,
    const u16* __restrict__ Mbh, const u16* __restrict__ Mbl,
    u16* __restrict__ Houth, u16* __restrict__ Houtl, const float* __restrict__ bias) {
  extern __shared__ u16 lds[];
  const int b = blockIdx.x;
  int g = b & 31, r = b >> 5;          // r: 0..15 -> bxm 0..3, bym 0..3
  mfma_body<1, true>(lds, XWTh, XWTl, Mbh, Mbl,
                     nullptr, Houth, Houtl, nullptr, nullptr, bias,
                     r >> 2, r & 3, g);
}

// ============ stage C: mode4 (half, 512): tmp = H @ T ============
__global__ __launch_bounds__(256, 2) void k_stageC(
    const u16* __restrict__ Wth, const u16* __restrict__ Wtl, int l,
    const u16* __restrict__ Hh, const u16* __restrict__ Hl,
    u16* __restrict__ tmph, u16* __restrict__ tmpl) {
  extern __shared__ u16 lds[];
  const int b = blockIdx.x;
  mfma_body<4, true>(lds, Wth + (size_t)(6 + l) * 65536, Wtl + (size_t)(6 + l) * 65536,
                     Hh, Hl, nullptr, tmph, tmpl, nullptr, nullptr, nullptr,
                     b & 127, b >> 7, 0);
}

// ============ stage D: A update. scaled!=0 (l0): MODE 5 applies the deferred scale ============
__global__ __launch_bounds__(256, 2) void k_stageD(
    const u16* __restrict__ tmph, const u16* __restrict__ tmpl,
    const u16* __restrict__ Hh, const u16* __restrict__ Hl,
    float* __restrict__ Abuf,
    const float* __restrict__ nrm, const float* __restrict__ dinv, int scaled) {
  extern __shared__ u16 lds[];
  const int b = blockIdx.x;
  int g = b & 31, r = b >> 5;
  if (scaled)
    mfma_body<5, true>(lds, tmph, tmpl, Hh, Hl, Abuf, nullptr, nullptr,
                       nrm, dinv, nullptr, r >> 2, r & 3, g);
  else
    mfma_body<3, true>(lds, tmph, tmpl, Hh, Hl, Abuf, nullptr, nullptr,
                       nullptr, nullptr, nullptr, r >> 2, r & 3, g);
}

// ============ fused maps ============
__global__ void k_maps(const float* __restrict__ Abuf, const float* __restrict__ emf,
                       const float* __restrict__ pmf, float* __restrict__ out) {
  __shared__ float sme[256], smp[256], red[256];
  const int g = blockIdx.x, tid = threadIdx.x, w = tid >> 6, lane = tid & 63;
  const int j0 = g * 256 + lane * 4;
  const float4 pmv = *(const float4*)&pmf[j0];
  const float4 emv = *(const float4*)&emf[j0];
  for (int it = 0; it < 64; ++it) {
    int nl = it * 4 + w;
    const float4 a = *(const float4*)&Abuf[((size_t)g * 256 + nl) * 256 + lane * 4];
    float me = a.x * pmv.x + a.y * pmv.y + a.z * pmv.z + a.w * pmv.w;
    float mp = a.x * emv.x + a.y * emv.y + a.z * emv.z + a.w * emv.w;
#pragma unroll
    for (int off = 32; off > 0; off >>= 1) {
      me += __shfl_down(me, off, 64);
      mp += __shfl_down(mp, off, 64);
    }
    if (lane == 0) { sme[nl] = me; smp[nl] = mp; }
  }
  __syncthreads();
  for (int which = 0; which < 2; ++which) {
    float v = which ? smp[tid] : sme[tid];
    red[tid] = v; __syncthreads();
    for (int s = 128; s > 0; s >>= 1) { if (tid < s) red[tid] = fminf(red[tid], red[tid + s]); __syncthreads(); }
    float mn = red[0]; __syncthreads();
    red[tid] = v; __syncthreads();
    for (int s = 128; s > 0; s >>= 1) { if (tid < s) red[tid] = fmaxf(red[tid], red[tid + s]); __syncthreads(); }
    float mx = red[0]; __syncthreads();
    float m = (v - mn) / (mx - mn + ZEROF);
    red[tid] = m; __syncthreads();
    for (int s = 128; s > 0; s >>= 1) { if (tid < s) red[tid] += red[tid + s]; __syncthreads(); }
    float sum = red[0]; __syncthreads();
    out[which * NND + g * 256 + tid] = m / (sum + ZEROF);
  }
}

// ================= launch =================
extern "C" void kernel_launch(void* const* d_in, const int* in_sizes, int n_in,
                              void* d_out, int out_size, void* d_ws, size_t ws_size,
                              hipStream_t stream) {
  const float* x = (const float*)d_in[0];
  const unsigned char* em_raw = (const unsigned char*)d_in[7];
  const unsigned char* pm_raw = (const unsigned char*)d_in[8];
  const float* W  = (const float*)d_in[9];
  const float* bg = (const float*)d_in[10];
  const float* T  = (const float*)d_in[11];
  float* out = (float*)d_out;
  const int E_ = in_sizes[2];

  const int nCvt = (2 * NND) / 256;          // 64
  const int nBkt = (E_ + 255) / 256;         // 512 for E=131072

  float* ws = (float*)d_ws;
  size_t o = 0;
  float* Abuf = ws + o; o += (size_t)NND * 256;
  u16* Mbh_l0 = (u16*)(ws + o); o += (size_t)NGRP * 3 * 65536 / 2;
  u16* Mbl_l0 = (u16*)(ws + o); o += (size_t)NGRP * 3 * 65536 / 2;
  u16* Mbh_l1 = (u16*)(ws + o); o += (size_t)NGRP * 3 * 65536 / 2;
  u16* Mbl_l1 = (u16*)(ws + o); o += (size_t)NGRP * 3 * 65536 / 2;
  u16* Hh   = (u16*)(ws + o); o += (size_t)NND * 256 / 2;
  u16* Hl   = (u16*)(ws + o); o += (size_t)NND * 256 / 2;
  u16* H2h  = (u16*)(ws + o); o += (size_t)NND * 256 / 2;
  u16* H2l  = (u16*)(ws + o); o += (size_t)NND * 256 / 2;
  u16* tmph = (u16*)(ws + o); o += (size_t)NND * 256 / 2;
  u16* tmpl = (u16*)(ws + o); o += (size_t)NND * 256 / 2;
  u16* XWTh = (u16*)(ws + o); o += (size_t)768 * NND / 2;
  u16* XWTl = (u16*)(ws + o); o += (size_t)768 * NND / 2;
  u16* Wth  = (u16*)(ws + o); o += (size_t)8 * 65536 / 2;
  u16* Wtl  = (u16*)(ws + o); o += (size_t)8 * 65536 / 2;
  float* nrm   = ws + o; o += NND;
  float* dinv  = ws + o; o += NND;
  float* Spart = ws + o; o += 128 * 256;
  float* emf   = ws + o; o += NND;
  float* pmf   = ws + o; o += NND;
  u16* sct     = (u16*)(ws + o); o += (size_t)nBkt * 768 / 2;
  uint2* recs  = (uint2*)(ws + o); o += (size_t)nBkt * 768 * 2;
  uint2* recs2 = (uint2*)(ws + o); o += (size_t)768 * 8 * CCAP * 2;
  int* bcnt2   = (int*)(ws + o); o += (size_t)768 * 8;

  const float* ew0 = (const float*)d_in[2];
  const float* ew1 = (const float*)d_in[4];
  const float* ew2 = (const float*)d_in[6];

  k_prep<<<nCvt + nBkt + 512 + 128, 256, 0, stream>>>(
      (const int*)d_in[1], (const int*)d_in[3], (const int*)d_in[5], em_raw, pm_raw,
      W, T, x, ew0, ew1, ew2, emf, pmf, Wth, Wtl, sct, recs,
      nrm, Spart, Hh, Hl, E_, nCvt, nBkt);

  k_reorder<<<1536, 256, 0, stream>>>(sct, recs, recs2, bcnt2, nBkt);

  // ---- layer 0 ----
  k_stageA<<<2176, 256, SM_FULL, stream>>>(Hh, Hl, Wth, Wtl, XWTh, XWTl,
                                           recs2, bcnt2, Mbh_l0, Mbl_l0, Abuf,
                                           x, Spart, nrm, dinv);
  k_stageB<<<512, 256, SM_HALF, stream>>>(XWTh, XWTl, Mbh_l0, Mbl_l0, H2h, H2l, bg);
  k_stageC<<<512, 256, SM_HALF, stream>>>(Wth, Wtl, 0, H2h, H2l, tmph, tmpl);
  k_stageD<<<512, 256, SM_HALF, stream>>>(tmph, tmpl, H2h, H2l, Abuf, nrm, dinv, 1);

  // ---- layer 1 ----
  k_stageA2<<<1536, 256, SM_FULL, stream>>>(H2h, H2l, Wth, Wtl, XWTh, XWTl,
                                            recs2, bcnt2, Abuf, Mbh_l1, Mbl_l1);
  k_stageB<<<512, 256, SM_HALF, stream>>>(XWTh, XWTl, Mbh_l1, Mbl_l1, Hh, Hl, bg + 768);
  k_stageC<<<512, 256, SM_HALF, stream>>>(Wth, Wtl, 1, Hh, Hl, tmph, tmpl);
  k_stageD<<<512, 256, SM_HALF, stream>>>(tmph, tmpl, Hh, Hl, Abuf, nullptr, nullptr, 0);

  k_maps<<<NGRP, 256, 0, stream>>>(Abuf, emf, pmf, out);
}